// Round 9
// baseline (1641.678 us; speedup 1.0000x reference)
//
#include <hip/hip_runtime.h>
#include <math.h>

#define HID 64
#define UH_LEN 15
#define N_INC 4

#define TWO_PI_365 0.0172142063f
#define TWO_PI_366 0.0171671554f
#define H24_PI     7.63943727f

typedef short short8 __attribute__((ext_vector_type(8)));
typedef float f32x4  __attribute__((ext_vector_type(4)));

__device__ __forceinline__ float frcp(float x){ return __builtin_amdgcn_rcpf(x); }
__device__ __forceinline__ float sigf(float x){ return frcp(1.0f + __expf(-x)); }
__device__ __forceinline__ float tanhfast(float x){ return 1.0f - 2.0f*frcp(__expf(2.0f*x)+1.0f); }

__device__ __forceinline__ unsigned short f2bf(float f){
    unsigned int u = __float_as_uint(f);
    u += 0x7FFF + ((u >> 16) & 1);
    return (unsigned short)(u >> 16);
}
__device__ __forceinline__ float bf2f(unsigned short h){
    return __uint_as_float(((unsigned int)h) << 16);
}

__device__ const float PLO[30] = {0.5f,0.7f,-2.0f,0.5f,0.05f,0.03f,0.0f,0.1f,0.02f,0.05f,0.0f,
                                  10.0f,5.0f,10.0f,10.0f,5.0f,0.1f,0.001f,0.01f,5.0f,1.0f,0.0f,
                                  0.0f,0.0f,0.0f,0.0f,0.0f,0.0f,1.0f,0.5f};
__device__ const float PHI[30] = {2.0f,1.4f,2.0f,2.0f,0.49f,0.19f,1.0f,1.0f,0.3f,0.5f,0.3f,
                                  300.0f,150.0f,500.0f,1000.0f,400.0f,0.75f,0.05f,0.35f,350.0f,5.0f,0.8f,
                                  0.1f,0.4f,0.2f,0.5f,0.4f,1.0f,6.0f,5.0f};
__device__ const float LOGT[15] = {0.0f,0.69314718f,1.09861229f,1.38629436f,1.60943791f,
                                   1.79175947f,1.94591015f,2.07944154f,2.19722458f,2.30258509f,
                                   2.39789527f,2.48490665f,2.56494936f,2.63905733f,2.70805020f};

__global__ void zero_kernel(float* __restrict__ p, int cnt){
    int i = blockIdx.x*256 + threadIdx.x;
    if (i < cnt) p[i] = 0.0f;
}

// ---------------------------------------------------------------------------
// x-pack: x_dyn [N][T][8] f32 -> xb [N*T] short8 (bf16). Fully parallel.
// ---------------------------------------------------------------------------
__global__ __launch_bounds__(256) void xpack_kernel(
    const float* __restrict__ x_dyn, unsigned short* __restrict__ xb, size_t NT)
{
    size_t i = (size_t)blockIdx.x*256 + threadIdx.x;
    if (i >= NT) return;
    const float4 a = ((const float4*)x_dyn)[2*i];
    const float4 b = ((const float4*)x_dyn)[2*i + 1];
    short8 o;
    o[0]=(short)f2bf(a.x); o[1]=(short)f2bf(a.y); o[2]=(short)f2bf(a.z); o[3]=(short)f2bf(a.w);
    o[4]=(short)f2bf(b.x); o[5]=(short)f2bf(b.y); o[6]=(short)f2bf(b.z); o[7]=(short)f2bf(b.w);
    ((short8*)xb)[i] = o;
}

// ---------------------------------------------------------------------------
// MFMA LSTM, UPB=16 (no redundant work). KEY r9 change: raw s_barrier with
// lgkmcnt(0)-only wait — __syncthreads() was draining vmcnt(0) every t,
// putting the streaming xb load's ~900cyc HBM latency inside all 730
// barriers (r8: redundant 2nd block cost only +185cyc -> ~90% stall).
// t-loop unrolled x2 with two static x registers: load at t consumed at t+2.
// ---------------------------------------------------------------------------
template<bool XB>
__global__ __launch_bounds__(256, 1) void lstm_kernel(
    const float* __restrict__ x_dyn, const unsigned short* __restrict__ xb,
    const float* __restrict__ x_static,
    const float* __restrict__ Wih, const float* __restrict__ Whh,
    const float* __restrict__ b_lstm, const float* __restrict__ Ws,
    const float* __restrict__ bs, const float* __restrict__ Wout,
    const float* __restrict__ bout, float* __restrict__ params,
    int N, int T, int DSTAT)
{
    __shared__ unsigned short h_lds[2][16*64];
    __shared__ float s_sh[16*64];

    const int tid = threadIdx.x;
    const int wv  = tid >> 6;
    const int ln  = tid & 63;
    const int q   = ln >> 4;
    const int r16 = ln & 15;
    const int u0  = blockIdx.x * 16;

    short8 wf[4][3];
    float  bias[4];
    #pragma unroll
    for (int g = 0; g < 4; ++g) {
        const int n = 64*g + 16*wv + r16;
        bias[g] = b_lstm[n];
        #pragma unroll
        for (int kb = 0; kb < 3; ++kb) {
            short8 w;
            #pragma unroll
            for (int e = 0; e < 8; ++e) {
                int k = 32*kb + 8*q + e;
                float v = 0.0f;
                if (k < 64)      v = Whh[n*64 + k];
                else if (k < 72) v = Wih[n*8 + (k - 64)];
                w[e] = (short)f2bf(v);
            }
            wf[g][kb] = w;
        }
    }

    for (int i = tid; i < 2*16*64; i += 256) ((unsigned short*)h_lds)[i] = 0;
    __syncthreads();

    float c[4] = {0.f, 0.f, 0.f, 0.f};

    const int ux = min(u0 + r16, N-1);
    const int jj   = 16*wv + r16;
    const int swz0 = (q       ^ (r16 & 7)) << 3;
    const int swz1 = ((q + 4) ^ (r16 & 7)) << 3;

// one LSTM timestep; RB = read-buffer index (t&1), XREG = x bf16 register
// (holds data loaded 2 iterations ago; reload for t+2 issued here, never
// drained at the barrier because the barrier waits lgkmcnt only)
#define LSTM_STEP(T_CUR, RB, XREG)                                              \
    {                                                                           \
        short8 a0 = *(const short8*)&h_lds[RB][r16*64 + swz0];                  \
        short8 a1 = *(const short8*)&h_lds[RB][r16*64 + swz1];                  \
        short8 a2 = XREG;                                                       \
        if (q == 0)                                                             \
            XREG = *(const short8*)(xb + ((size_t)ux*T + min((T_CUR)+2, T-1))*8);\
        f32x4 acc[4];                                                           \
        _Pragma("unroll")                                                       \
        for (int gg = 0; gg < 4; ++gg) {                                        \
            f32x4 a; a[0]=bias[gg]; a[1]=bias[gg]; a[2]=bias[gg]; a[3]=bias[gg];\
            a = __builtin_amdgcn_mfma_f32_16x16x32_bf16(a2, wf[gg][2], a,0,0,0);\
            a = __builtin_amdgcn_mfma_f32_16x16x32_bf16(a0, wf[gg][0], a,0,0,0);\
            a = __builtin_amdgcn_mfma_f32_16x16x32_bf16(a1, wf[gg][1], a,0,0,0);\
            acc[gg] = a;                                                        \
        }                                                                       \
        _Pragma("unroll")                                                       \
        for (int r = 0; r < 4; ++r) {                                           \
            float iv = sigf(acc[0][r]);                                         \
            float fv = sigf(acc[1][r]);                                         \
            float gv = tanhfast(acc[2][r]);                                     \
            float ov = sigf(acc[3][r]);                                         \
            c[r] = fv*c[r] + iv*gv;                                             \
            float hv = ov*tanhfast(c[r]);                                       \
            int u = 4*q + r;                                                    \
            h_lds[(RB)^1][u*64 + (((jj>>3) ^ (u&7))<<3) + (jj&7)] = f2bf(hv);   \
        }                                                                       \
        asm volatile("s_waitcnt lgkmcnt(0)" ::: "memory");                      \
        __builtin_amdgcn_s_barrier();                                           \
    }

    if constexpr (XB) {
        short8 x0, x1;
        #pragma unroll
        for (int e = 0; e < 8; ++e) { x0[e] = 0; x1[e] = 0; }
        if (q == 0) {
            x0 = *(const short8*)(xb + ((size_t)ux*T)*8);
            x1 = *(const short8*)(xb + ((size_t)ux*T + min(1, T-1))*8);
        }
        int t = 0;
        for (; t + 1 < T; t += 2) {
            LSTM_STEP(t,   0, x0);
            LSTM_STEP(t+1, 1, x1);
        }
        if (t < T) LSTM_STEP(t, 0, x0);
    } else {
        // fallback: f32 x loads, safe __syncthreads (rarely taken tier)
        float xf[8];
        if (q == 0) {
            const float* p = x_dyn + ((size_t)ux * T) * 8;
            #pragma unroll
            for (int e = 0; e < 8; ++e) xf[e] = p[e];
        }
        for (int t = 0; t < T; ++t) {
            short8 a2;
            #pragma unroll
            for (int e = 0; e < 8; ++e) a2[e] = (q == 0) ? (short)f2bf(xf[e]) : (short)0;
            const int rb = t & 1;
            short8 a0 = *(const short8*)&h_lds[rb][r16*64 + swz0];
            short8 a1 = *(const short8*)&h_lds[rb][r16*64 + swz1];
            if (q == 0 && t + 1 < T) {
                const float* p = x_dyn + ((size_t)ux * T + (t+1)) * 8;
                #pragma unroll
                for (int e = 0; e < 8; ++e) xf[e] = p[e];
            }
            f32x4 acc[4];
            #pragma unroll
            for (int g = 0; g < 4; ++g) {
                f32x4 a; a[0]=bias[g]; a[1]=bias[g]; a[2]=bias[g]; a[3]=bias[g];
                a = __builtin_amdgcn_mfma_f32_16x16x32_bf16(a2, wf[g][2], a, 0, 0, 0);
                a = __builtin_amdgcn_mfma_f32_16x16x32_bf16(a0, wf[g][0], a, 0, 0, 0);
                a = __builtin_amdgcn_mfma_f32_16x16x32_bf16(a1, wf[g][1], a, 0, 0, 0);
                acc[g] = a;
            }
            const int wb = rb ^ 1;
            #pragma unroll
            for (int r = 0; r < 4; ++r) {
                float iv = sigf(acc[0][r]);
                float fv = sigf(acc[1][r]);
                float gv = tanhfast(acc[2][r]);
                float ov = sigf(acc[3][r]);
                c[r] = fv*c[r] + iv*gv;
                float hv = ov*tanhfast(c[r]);
                int u = 4*q + r;
                h_lds[wb][u*64 + (((jj>>3) ^ (u&7))<<3) + (jj&7)] = f2bf(hv);
            }
            __syncthreads();
        }
    }
#undef LSTM_STEP

    const int fb = T & 1;
    for (int uu = 0; uu < 4; ++uu) {
        int ul = wv*4 + uu;
        int u  = min(u0 + ul, N-1);
        float a = bs[ln];
        for (int k = 0; k < DSTAT; ++k)
            a = fmaf(x_static[(size_t)u*DSTAT + k], Ws[ln*DSTAT + k], a);
        s_sh[ul*64 + ln] = tanhfast(a);
    }
    if (ln < 30) {
        for (int uu = 0; uu < 4; ++uu) {
            int ul = wv*4 + uu;
            int unit = u0 + ul;
            if (unit < N) {
                float raw = bout[ln];
                #pragma unroll 8
                for (int m = 0; m < 64; ++m) {
                    float hm = bf2f(h_lds[fb][ul*64 + (((m>>3) ^ (ul&7))<<3) + (m&7)]);
                    float sm = s_sh[ul*64 + m];
                    raw = fmaf(hm, Wout[ln*128 + m],      raw);
                    raw = fmaf(sm, Wout[ln*128 + 64 + m], raw);
                }
                float g = sigf(raw);
                params[ln*N + unit] = PLO[ln] + g*(PHI[ln] - PLO[ln]);
            }
        }
    }
}

// ---------------------------------------------------------------------------
// Pack kernel: per (n,t) float4 (prcp, tavg, PET, melt_factor).
// ---------------------------------------------------------------------------
__global__ __launch_bounds__(256) void pack_kernel(
    const float* __restrict__ prcp, const float* __restrict__ tavg,
    const int* __restrict__ doy, const float* __restrict__ lat_rad,
    const float* __restrict__ P,
    float4* __restrict__ pack, int N, int T)
{
    const int n = blockIdx.y;
    const int t = blockIdx.x*256 + threadIdx.x;
    if (t >= T) return;
    const float pr = prcp[(size_t)n*T + t];
    const float ta = tavg[(size_t)n*T + t];
    const float dy = (float)doy[(size_t)n*T + t];
    const float tanlat = __tanf(lat_rad[n]);
    const float HAMON  = P[n];
    const float MFMAX  = P[3*N + n], MFMIN = P[4*N + n];
    float decl  = 0.4093f*__sinf(TWO_PI_365*dy - 1.405f);
    float cosw  = fminf(fmaxf(-tanlat*__tanf(decl), -0.9999f), 0.9999f);
    float daylen= acosf(cosw)*H24_PI;
    float esat  = 0.6108f*__expf(17.27f*ta*frcp(ta + 237.3f));
    float pet   = fmaxf(HAMON*29.8f*daylen*esat*frcp(ta + 273.2f), 0.0f);
    float mf    = 0.5f*(MFMAX + MFMIN) + 0.5f*(MFMAX - MFMIN)*__sinf(TWO_PI_366*dy);
    pack[(size_t)n*T + t] = make_float4(pr, ta, pet, mf);
}

// ---------------------------------------------------------------------------
// Physics, U=2 per thread, packed+split only. Two independent chains
// interleave in the dependency-stall slots of the lean packed loop
// (1 float4 load + 1 float2 store + ~90 VALU per unit per t).
// ---------------------------------------------------------------------------
__global__ __launch_bounds__(64, 1) void physics2_kernel(
    const float* __restrict__ elev_m, const float* __restrict__ P,
    const float4* __restrict__ pack, float2* __restrict__ sbA, int N, int T)
{
    const int g  = blockIdx.x*64 + threadIdx.x;
    const int n0 = 2*g;
    if (n0 >= N) return;
    int nn[2]; nn[0] = n0; nn[1] = min(n0 + 1, N - 1);

    float SCF[2],PXTEMP[2],MBASE[2],TIPM[2],PLWHC[2],NMF[2],DAYGM[2];
    float UZTWM[2],UZFWM[2],LZTWM[2],LZFPM[2],LZFSM[2];
    float mrosk[2],iUZTWM[2],itwm[2],twm[2],ilzmax[2],iside[2],pfac[2];
    float kp[2],ks[2],ku[2],pm[2],ZPERC[2],REXP[2],PFREE[2],PCTIM[2],ADIMP[2];
    const float dtq = 1.0f / (float)N_INC;
    #pragma unroll
    for (int u = 0; u < 2; ++u) {
        const int n = nn[u];
        SCF[u]=P[1*N+n]; PXTEMP[u]=P[2*N+n];
        mrosk[u]=P[5*N+n]*__expf(-elev_m[n]*(1.0f/8434.0f))*0.0125f;
        MBASE[u]=P[6*N+n]; TIPM[u]=P[7*N+n]; PLWHC[u]=P[8*N+n];
        NMF[u]=P[9*N+n]; DAYGM[u]=P[10*N+n];
        UZTWM[u]=P[11*N+n]; UZFWM[u]=P[12*N+n]; LZTWM[u]=P[13*N+n];
        LZFPM[u]=P[14*N+n]; LZFSM[u]=P[15*N+n];
        ku[u]=P[16*N+n]*dtq;
        float LZPK=P[17*N+n], LZSK=P[18*N+n];
        kp[u]=LZPK*dtq; ks[u]=LZSK*dtq;
        pm[u]=(LZFPM[u]*LZPK + LZFSM[u]*LZSK)*dtq*frcp(UZFWM[u]);
        ZPERC[u]=P[19*N+n]; REXP[u]=P[20*N+n]; PFREE[u]=P[21*N+n];
        PCTIM[u]=P[22*N+n]; ADIMP[u]=P[23*N+n];
        iside[u]=frcp(1.0f + P[25*N+n]);
        pfac[u]=(1.0f - PCTIM[u] - ADIMP[u])*dtq;
        iUZTWM[u]=frcp(UZTWM[u]);
        twm[u]=UZTWM[u]+LZTWM[u]; itwm[u]=frcp(twm[u]);
        ilzmax[u]=frcp(LZTWM[u]+LZFPM[u]+LZFSM[u]);
    }

    float wi[2]={0.f,0.f}, wqv[2]={0.f,0.f}, ati[2]={0.f,0.f};
    float uztwc[2],uzfwc[2],lztwc[2],lzfpc[2],lzfsc[2],adimc[2];
    #pragma unroll
    for (int u = 0; u < 2; ++u) {
        uztwc[u]=0.5f*UZTWM[u]; uzfwc[u]=0.5f*UZFWM[u]; lztwc[u]=0.5f*LZTWM[u];
        lzfpc[u]=0.5f*LZFPM[u]; lzfsc[u]=0.5f*LZFSM[u]; adimc[u]=0.5f*twm[u];
    }

    const float4* pk0 = pack + (size_t)nn[0]*T;
    const float4* pk1 = pack + (size_t)nn[1]*T;
    float2* sb0 = sbA + (size_t)nn[0]*T;
    float2* sb1 = sbA + (size_t)nn[1]*T;

    float4 cur[2], nx1[2];
    cur[0] = pk0[0]; cur[1] = pk1[0];
    const int t1i = min(1, T-1);
    nx1[0] = pk0[t1i]; nx1[1] = pk1[t1i];

    for (int t = 0; t < T; ++t) {
        const int t2 = min(t + 2, T - 1);
        float4 nx2_0 = pk0[t2];
        float4 nx2_1 = pk1[t2];

        float sfo[2], bso[2];
        #pragma unroll
        for (int u = 0; u < 2; ++u) {
            const float pr = cur[u].x, ta = cur[u].y, pet = cur[u].z, mf = cur[u].w;

            // --- Snow17 ---
            bool is_snow = (ta <= PXTEMP[u]);
            float ps    = is_snow ? pr*SCF[u] : 0.0f;
            float prain = is_snow ? 0.0f : pr;
            wi[u] += ps;
            ati[u] += TIPM[u]*(fminf(ta, 0.0f) - ati[u]);
            float mros = mrosk[u]*fmaxf(ta, 0.0f)*((!is_snow && wi[u] > 0.0f) ? prain : 0.0f);
            float melt = fminf(fmaxf(mf*fmaxf(ta - MBASE[u], 0.0f) + mros
                                     - NMF[u]*fmaxf(-ati[u], 0.0f), 0.0f), wi[u]);
            wi[u] -= melt;
            float gm = fminf(DAYGM[u], wi[u]);
            wi[u] -= gm;
            float rop   = (wi[u] > 0.0f) ? prain : 0.0f;
            float rfree = prain - rop;
            wqv[u] += melt + rop;
            float outq = fmaxf(wqv[u] - PLWHC[u]*wi[u], 0.0f);
            wqv[u] -= outq;
            float eff = outq + gm + rfree;

            // --- SAC-SMA ---
            float e1 = fminf(pet*uztwc[u]*iUZTWM[u], uztwc[u]);
            uztwc[u] -= e1;
            float red = pet - e1;
            float e2 = fminf(red, uzfwc[u]);
            uzfwc[u] -= e2; red -= e2;
            float e3 = fminf(red*lztwc[u]*itwm[u], lztwc[u]);
            lztwc[u] -= e3;
            float roimp  = eff*PCTIM[u];
            float padimp = eff*ADIMP[u];
            adimc[u] += padimp;
            float ratio = fminf(fmaxf(adimc[u]*itwm[u], 0.0f), 1.0f);
            float adsur = padimp*ratio*ratio;
            adimc[u] = fminf(adimc[u] - adsur, twm[u]);
            float surf = roimp + adsur;
            float base = 0.0f;
            float pinc = eff*pfac[u];
            #pragma unroll
            for (int inc = 0; inc < N_INC; ++inc) {
                float bfp = lzfpc[u]*kp[u];
                float bfs = lzfsc[u]*ks[u];
                lzfpc[u] -= bfp; lzfsc[u] -= bfs;
                base += (bfp + bfs)*iside[u];
                float qif = uzfwc[u]*ku[u];
                uzfwc[u] -= qif; surf += qif;
                float lz_def = (LZTWM[u]-lztwc[u]) + (LZFPM[u]-lzfpc[u]) + (LZFSM[u]-lzfsc[u]);
                float defr = fminf(fmaxf(lz_def*ilzmax[u], 1e-6f), 1.0f);
                float perc = pm[u]*fmaf(ZPERC[u], __expf(REXP[u]*__logf(defr)), 1.0f)*uzfwc[u];
                perc = fminf(fminf(perc, uzfwc[u]), fmaxf(lz_def, 0.0f));
                uzfwc[u] -= perc;
                float pfree = perc*PFREE[u];
                lztwc[u] += perc - pfree;
                float ex = fmaxf(lztwc[u] - LZTWM[u], 0.0f);
                lztwc[u] -= ex; pfree += ex;
                float dp  = fmaxf(LZFPM[u] - lzfpc[u], 0.0f);
                float dsx = fmaxf(LZFSM[u] - lzfsc[u], 0.0f);
                float fr  = dp*frcp(fmaxf(dp + dsx, 1e-6f));
                lzfpc[u] += pfree*fr;
                lzfsc[u] += pfree*(1.0f - fr);
                float exq = fmaxf(lzfpc[u] - LZFPM[u], 0.0f);
                lzfpc[u] -= exq; lzfsc[u] += exq;
                float exs = fmaxf(lzfsc[u] - LZFSM[u], 0.0f);
                lzfsc[u] -= exs; surf += exs;
                uztwc[u] += pinc;
                float exu = fmaxf(uztwc[u] - UZTWM[u], 0.0f);
                uztwc[u] -= exu; uzfwc[u] += exu;
                float exf = fmaxf(uzfwc[u] - UZFWM[u], 0.0f);
                uzfwc[u] -= exf; surf += exf;
            }
            sfo[u] = surf; bso[u] = base;
        }

        sb0[t] = make_float2(sfo[0], bso[0]);
        sb1[t] = make_float2(sfo[1], bso[1]);
        cur[0] = nx1[0]; cur[1] = nx1[1];
        nx1[0] = nx2_0;  nx1[1] = nx2_1;
    }
}

// ---------------------------------------------------------------------------
// Physics U=1 fallback (tier2/3), unchanged from r8.
// ---------------------------------------------------------------------------
template<bool SPLIT>
__global__ __launch_bounds__(64, 1) void physics_kernel(
    const float* __restrict__ prcp, const float* __restrict__ tavg,
    const int*   __restrict__ doy,  const float* __restrict__ elev_m,
    const float* __restrict__ lat_rad, const float* __restrict__ area_w,
    const int*   __restrict__ basin_idx, const float* __restrict__ P,
    float* __restrict__ surfA, float* __restrict__ baseA,
    float* __restrict__ out, int N, int T, int B)
{
    int n = blockIdx.x*64 + threadIdx.x;
    if (n >= N) return;

    const float HAMON = P[ 0*N+n], SCF   = P[ 1*N+n], PXTEMP= P[ 2*N+n];
    const float MFMAX = P[ 3*N+n], MFMIN = P[ 4*N+n];
    const float MBASE = P[ 6*N+n], TIPM  = P[ 7*N+n], PLWHC = P[ 8*N+n];
    const float NMF   = P[ 9*N+n], DAYGM = P[10*N+n];
    const float UZTWM = P[11*N+n], UZFWM = P[12*N+n], LZTWM = P[13*N+n];
    const float LZFPM = P[14*N+n], LZFSM = P[15*N+n], UZK   = P[16*N+n];
    const float LZPK  = P[17*N+n], LZSK  = P[18*N+n], ZPERC = P[19*N+n];
    const float REXP  = P[20*N+n], PFREE = P[21*N+n], PCTIM = P[22*N+n];
    const float ADIMP = P[23*N+n], SIDE  = P[25*N+n];
    const float UH_N  = P[28*N+n], UH_TAU= P[29*N+n];

    const float mrosk  = P[5*N+n]*__expf(-elev_m[n]*(1.0f/8434.0f))*0.0125f;
    const float tanlat = __tanf(lat_rad[n]);
    const float wA     = area_w[n];
    const int   bi     = basin_idx[n];
    const float mfa = 0.5f*(MFMAX + MFMIN), mfb = 0.5f*(MFMAX - MFMIN);

    float uh[UH_LEN];
    float hist[UH_LEN-1];
    if (!SPLIT) {
        float uhs = 0.0f;
        const float inv_tau = frcp(UH_TAU);
        #pragma unroll
        for (int l = 0; l < UH_LEN; ++l) {
            uh[l] = __expf((UH_N - 1.0f)*LOGT[l] - (float)(l+1)*inv_tau);
            uhs += uh[l];
        }
        float inv_uhs = frcp(uhs);
        #pragma unroll
        for (int l = 0; l < UH_LEN; ++l) uh[l] *= inv_uhs;
        #pragma unroll
        for (int l = 0; l < UH_LEN-1; ++l) hist[l] = 0.0f;
    }

    const float dtq       = 1.0f / (float)N_INC;
    const float kp        = LZPK*dtq, ks = LZSK*dtq, ku = UZK*dtq;
    const float twm_sum   = UZTWM + LZTWM;
    const float inv_uztwm = frcp(UZTWM);
    const float inv_twm   = frcp(twm_sum);
    const float inv_lzmax = frcp(LZTWM + LZFPM + LZFSM);
    const float inv_side  = frcp(1.0f + SIDE);
    const float pinc_fac  = (1.0f - PCTIM - ADIMP)*dtq;
    const float pm        = (LZFPM*LZPK + LZFSM*LZSK)*dtq*frcp(UZFWM);

    float wi = 0.0f, wq = 0.0f, ati = 0.0f;
    float uztwc = 0.5f*UZTWM, uzfwc = 0.5f*UZFWM, lztwc = 0.5f*LZTWM;
    float lzfpc = 0.5f*LZFPM, lzfsc = 0.5f*LZFSM, adimc = 0.5f*twm_sum;

    float* q_gauge = out;
    float* q_base  = out + (size_t)B*T;
    float* q_unit  = out + (size_t)2*B*T;

    float pr_c = prcp[(size_t)n*T];
    float ta_c = tavg[(size_t)n*T];
    float dy0 = (float)doy[(size_t)n*T];
    float decl0 = 0.4093f*__sinf(TWO_PI_365*dy0 - 1.405f);
    float cosw0 = fminf(fmaxf(-tanlat*__tanf(decl0), -0.9999f), 0.9999f);
    float pet_c = fmaxf(HAMON*29.8f*(acosf(cosw0)*H24_PI)
                        *0.6108f*__expf(17.27f*ta_c*frcp(ta_c + 237.3f))
                        *frcp(ta_c + 273.2f), 0.0f);
    float mf_c  = mfa + mfb*__sinf(TWO_PI_366*dy0);

    for (int t = 0; t < T; ++t) {
        const int tn = min(t + 1, T - 1);
        float pr_n = prcp[(size_t)n*T + tn];
        float ta_n = tavg[(size_t)n*T + tn];
        float dy_n = (float)doy[(size_t)n*T + tn];
        const float pr = pr_c, ta = ta_c, pet = pet_c, mf = mf_c;

        bool is_snow = (ta <= PXTEMP);
        float ps    = is_snow ? pr*SCF : 0.0f;
        float prain = is_snow ? 0.0f   : pr;
        wi += ps;
        ati += TIPM*(fminf(ta, 0.0f) - ati);
        float mros = mrosk*fmaxf(ta, 0.0f)*((!is_snow && wi > 0.0f) ? prain : 0.0f);
        float melt = fminf(fmaxf(mf*fmaxf(ta - MBASE, 0.0f) + mros - NMF*fmaxf(-ati, 0.0f), 0.0f), wi);
        wi -= melt;
        float gm = fminf(DAYGM, wi);
        wi -= gm;
        float rop   = (wi > 0.0f) ? prain : 0.0f;
        float rfree = prain - rop;
        wq += melt + rop;
        float outq = fmaxf(wq - PLWHC*wi, 0.0f);
        wq -= outq;
        float eff = outq + gm + rfree;

        float e1 = fminf(pet*uztwc*inv_uztwm, uztwc);
        uztwc -= e1;
        float red = pet - e1;
        float e2 = fminf(red, uzfwc);
        uzfwc -= e2; red -= e2;
        float e3 = fminf(red*lztwc*inv_twm, lztwc);
        lztwc -= e3;
        float roimp  = eff*PCTIM;
        float padimp = eff*ADIMP;
        adimc += padimp;
        float ratio = fminf(fmaxf(adimc*inv_twm, 0.0f), 1.0f);
        float adsur = padimp*ratio*ratio;
        adimc = fminf(adimc - adsur, twm_sum);
        float surf = roimp + adsur;
        float base = 0.0f;
        float pinc = eff*pinc_fac;
        #pragma unroll
        for (int inc = 0; inc < N_INC; ++inc) {
            float bfp = lzfpc*kp;
            float bfs = lzfsc*ks;
            lzfpc -= bfp; lzfsc -= bfs;
            base += (bfp + bfs)*inv_side;
            float qif = uzfwc*ku;
            uzfwc -= qif; surf += qif;
            float lz_def = (LZTWM - lztwc) + (LZFPM - lzfpc) + (LZFSM - lzfsc);
            float defr = fminf(fmaxf(lz_def*inv_lzmax, 1e-6f), 1.0f);
            float perc = pm*fmaf(ZPERC, __expf(REXP*__logf(defr)), 1.0f)*uzfwc;
            perc = fminf(fminf(perc, uzfwc), fmaxf(lz_def, 0.0f));
            uzfwc -= perc;
            float pfree = perc*PFREE;
            lztwc += perc - pfree;
            float ex = fmaxf(lztwc - LZTWM, 0.0f);
            lztwc -= ex; pfree += ex;
            float dp  = fmaxf(LZFPM - lzfpc, 0.0f);
            float dsx = fmaxf(LZFSM - lzfsc, 0.0f);
            float fr  = dp*frcp(fmaxf(dp + dsx, 1e-6f));
            lzfpc += pfree*fr;
            lzfsc += pfree*(1.0f - fr);
            float exq = fmaxf(lzfpc - LZFPM, 0.0f);
            lzfpc -= exq; lzfsc += exq;
            float exs = fmaxf(lzfsc - LZFSM, 0.0f);
            lzfsc -= exs; surf += exs;
            uztwc += pinc;
            float exu = fmaxf(uztwc - UZTWM, 0.0f);
            uztwc -= exu; uzfwc += exu;
            float exf = fmaxf(uzfwc - UZFWM, 0.0f);
            uzfwc -= exf; surf += exf;
        }

        if (SPLIT) {
            surfA[(size_t)n*T + t] = surf;
            baseA[(size_t)n*T + t] = base;
        } else {
            float qv = uh[0]*surf;
            #pragma unroll
            for (int l = 1; l < UH_LEN; ++l) qv = fmaf(uh[l], hist[l-1], qv);
            #pragma unroll
            for (int l = UH_LEN-2; l >= 1; --l) hist[l] = hist[l-1];
            hist[0] = surf;
            qv += base;
            q_unit[(size_t)n*T + t] = qv;
            atomicAdd(&q_gauge[(size_t)bi*T + t], qv*wA);
            atomicAdd(&q_base [(size_t)bi*T + t], base*wA);
        }

        float decl = 0.4093f*__sinf(TWO_PI_365*dy_n - 1.405f);
        float cosw = fminf(fmaxf(-tanlat*__tanf(decl), -0.9999f), 0.9999f);
        pet_c = fmaxf(HAMON*29.8f*(acosf(cosw)*H24_PI)
                      *0.6108f*__expf(17.27f*ta_n*frcp(ta_n + 237.3f))
                      *frcp(ta_n + 273.2f), 0.0f);
        mf_c = mfa + mfb*__sinf(TWO_PI_366*dy_n);
        pr_c = pr_n; ta_c = ta_n;
    }
}

// ---------------------------------------------------------------------------
// Routing + gauge segment-sum: fully parallel over (n, t).
// ---------------------------------------------------------------------------
template<bool PACKED>
__global__ __launch_bounds__(256) void route_kernel(
    const float2* __restrict__ sbA,
    const float* __restrict__ surfA, const float* __restrict__ baseA,
    const float* __restrict__ P, const float* __restrict__ area_w,
    const int* __restrict__ basin_idx,
    float* __restrict__ out, int N, int T, int B)
{
    __shared__ float uh_sh[UH_LEN];
    __shared__ float wA_sh;
    __shared__ int   bi_sh;

    const int n = blockIdx.y;
    const int t = blockIdx.x*256 + threadIdx.x;

    if (threadIdx.x == 0) {
        float UH_N = P[28*N + n], UH_TAU = P[29*N + n];
        float inv_tau = frcp(UH_TAU);
        float tmp[UH_LEN], s = 0.f;
        #pragma unroll
        for (int l = 0; l < UH_LEN; ++l) {
            tmp[l] = __expf((UH_N - 1.0f)*LOGT[l] - (float)(l+1)*inv_tau);
            s += tmp[l];
        }
        float is = frcp(s);
        #pragma unroll
        for (int l = 0; l < UH_LEN; ++l) uh_sh[l] = tmp[l]*is;
        wA_sh = area_w[n];
        bi_sh = basin_idx[n];
    }
    __syncthreads();
    if (t >= T) return;

    float base, acc = 0.f;
    if (PACKED) {
        const float2* sb = sbA + (size_t)n*T;
        base = sb[t].y;
        #pragma unroll
        for (int l = 0; l < UH_LEN; ++l) {
            int tt = t - l;
            if (tt >= 0) acc = fmaf(uh_sh[l], sb[tt].x, acc);
        }
    } else {
        base = baseA[(size_t)n*T + t];
        #pragma unroll
        for (int l = 0; l < UH_LEN; ++l) {
            int tt = t - l;
            if (tt >= 0) acc = fmaf(uh_sh[l], surfA[(size_t)n*T + tt], acc);
        }
    }
    const float qv = acc + base;

    float* q_gauge = out;
    float* q_base  = out + (size_t)B*T;
    float* q_unit  = out + (size_t)2*B*T;

    q_unit[(size_t)n*T + t] = qv;
    atomicAdd(&q_gauge[(size_t)bi_sh*T + t], qv*wA_sh);
    atomicAdd(&q_base [(size_t)bi_sh*T + t], base*wA_sh);
}

static inline size_t align256(size_t x){ return (x + 255) & ~(size_t)255; }

extern "C" void kernel_launch(void* const* d_in, const int* in_sizes, int n_in,
                              void* d_out, int out_size, void* d_ws, size_t ws_size,
                              hipStream_t stream) {
    const float* x_dyn    = (const float*)d_in[0];
    const float* x_static = (const float*)d_in[1];
    const float* prcp     = (const float*)d_in[2];
    const float* tavg     = (const float*)d_in[3];
    const int*   doy      = (const int*)  d_in[4];
    const float* elev_m   = (const float*)d_in[5];
    const float* lat_rad  = (const float*)d_in[6];
    const float* area_w   = (const float*)d_in[7];
    const int*   basin_ix = (const int*)  d_in[8];
    const float* Wih      = (const float*)d_in[10];
    const float* Whh      = (const float*)d_in[11];
    const float* b_lstm   = (const float*)d_in[12];
    const float* Ws       = (const float*)d_in[13];
    const float* bs       = (const float*)d_in[14];
    const float* Wout     = (const float*)d_in[15];
    const float* bout     = (const float*)d_in[16];

    const int N = in_sizes[7];
    const int T = in_sizes[2] / N;
    const int DSTAT = in_sizes[1] / N;
    const size_t NT = (size_t)N * T;
    const int B = (out_size - (int)NT) / (2 * T);

    char* wsb = (char*)d_ws;
    float* params = (float*)wsb;
    const size_t off_prm = align256(30*(size_t)N*sizeof(float));

    // tier0: params | xb(16NT) | pack(16NT) | sb(8NT)
    const size_t off_xb0   = off_prm;
    const size_t off_pack0 = align256(off_xb0 + NT*16);
    const size_t off_sb0   = align256(off_pack0 + NT*16);
    const size_t need0     = off_sb0 + NT*8;
    // tier1: params | pack | sb (no xb)
    const size_t off_pack1 = off_prm;
    const size_t off_sb1   = align256(off_pack1 + NT*16);
    const size_t need1     = off_sb1 + NT*8;
    // tier2: params | surf | base
    const size_t off_surf2 = off_prm;
    const size_t off_base2 = off_surf2 + NT*4;
    const size_t need2     = off_base2 + NT*4;

    const int tier = (ws_size >= need0) ? 0 : (ws_size >= need1) ? 1 :
                     (ws_size >= need2) ? 2 : 3;

    float* out = (float*)d_out;
    const int zc = 2 * B * T;
    zero_kernel<<<(zc + 255)/256, 256, 0, stream>>>(out, zc);

    const int blocks_lstm = (N + 15) / 16;    // UPB=16, no redundant work
    const int npairs = (N + 1) / 2;
    const int p2blocks = (npairs + 63) / 64;
    const int pblocks = (N + 63) / 64;
    dim3 rg((T + 255)/256, N);

    if (tier == 0) {
        unsigned short* xbp = (unsigned short*)(wsb + off_xb0);
        float4* pack = (float4*)(wsb + off_pack0);
        float2* sbA  = (float2*)(wsb + off_sb0);
        xpack_kernel<<<(int)((NT + 255)/256), 256, 0, stream>>>(x_dyn, xbp, NT);
        lstm_kernel<true><<<blocks_lstm, 256, 0, stream>>>(
            x_dyn, xbp, x_static, Wih, Whh, b_lstm, Ws, bs, Wout, bout,
            params, N, T, DSTAT);
        pack_kernel<<<rg, 256, 0, stream>>>(prcp, tavg, doy, lat_rad, params, pack, N, T);
        physics2_kernel<<<p2blocks, 64, 0, stream>>>(elev_m, params, pack, sbA, N, T);
        route_kernel<true><<<rg, 256, 0, stream>>>(sbA, nullptr, nullptr, params, area_w,
                                                   basin_ix, out, N, T, B);
    } else if (tier == 1) {
        float4* pack = (float4*)(wsb + off_pack1);
        float2* sbA  = (float2*)(wsb + off_sb1);
        lstm_kernel<false><<<blocks_lstm, 256, 0, stream>>>(
            x_dyn, nullptr, x_static, Wih, Whh, b_lstm, Ws, bs, Wout, bout,
            params, N, T, DSTAT);
        pack_kernel<<<rg, 256, 0, stream>>>(prcp, tavg, doy, lat_rad, params, pack, N, T);
        physics2_kernel<<<p2blocks, 64, 0, stream>>>(elev_m, params, pack, sbA, N, T);
        route_kernel<true><<<rg, 256, 0, stream>>>(sbA, nullptr, nullptr, params, area_w,
                                                   basin_ix, out, N, T, B);
    } else if (tier == 2) {
        float* surfA = (float*)(wsb + off_surf2);
        float* baseA = (float*)(wsb + off_base2);
        lstm_kernel<false><<<blocks_lstm, 256, 0, stream>>>(
            x_dyn, nullptr, x_static, Wih, Whh, b_lstm, Ws, bs, Wout, bout,
            params, N, T, DSTAT);
        physics_kernel<true><<<pblocks, 64, 0, stream>>>(
            prcp, tavg, doy, elev_m, lat_rad, area_w, basin_ix, params,
            surfA, baseA, out, N, T, B);
        route_kernel<false><<<rg, 256, 0, stream>>>(nullptr, surfA, baseA, params, area_w,
                                                    basin_ix, out, N, T, B);
    } else {
        lstm_kernel<false><<<blocks_lstm, 256, 0, stream>>>(
            x_dyn, nullptr, x_static, Wih, Whh, b_lstm, Ws, bs, Wout, bout,
            params, N, T, DSTAT);
        physics_kernel<false><<<pblocks, 64, 0, stream>>>(
            prcp, tavg, doy, elev_m, lat_rad, area_w, basin_ix, params,
            nullptr, nullptr, out, N, T, B);
    }
}

// Round 10
// 1063.718 us; speedup vs baseline: 1.5433x; 1.5433x over previous
//
#include <hip/hip_runtime.h>
#include <math.h>

#define HID 64
#define UH_LEN 15
#define N_INC 4

#define TWO_PI_365 0.0172142063f
#define TWO_PI_366 0.0171671554f
#define H24_PI     7.63943727f

typedef short short8 __attribute__((ext_vector_type(8)));
typedef float f32x4  __attribute__((ext_vector_type(4)));

__device__ __forceinline__ float frcp(float x){ return __builtin_amdgcn_rcpf(x); }
__device__ __forceinline__ float sigf(float x){ return frcp(1.0f + __expf(-x)); }
__device__ __forceinline__ float tanhfast(float x){ return 1.0f - 2.0f*frcp(__expf(2.0f*x)+1.0f); }

__device__ __forceinline__ unsigned short f2bf(float f){
    unsigned int u = __float_as_uint(f);
    u += 0x7FFF + ((u >> 16) & 1);
    return (unsigned short)(u >> 16);
}
__device__ __forceinline__ float bf2f(unsigned short h){
    return __uint_as_float(((unsigned int)h) << 16);
}

__device__ const float PLO[30] = {0.5f,0.7f,-2.0f,0.5f,0.05f,0.03f,0.0f,0.1f,0.02f,0.05f,0.0f,
                                  10.0f,5.0f,10.0f,10.0f,5.0f,0.1f,0.001f,0.01f,5.0f,1.0f,0.0f,
                                  0.0f,0.0f,0.0f,0.0f,0.0f,0.0f,1.0f,0.5f};
__device__ const float PHI[30] = {2.0f,1.4f,2.0f,2.0f,0.49f,0.19f,1.0f,1.0f,0.3f,0.5f,0.3f,
                                  300.0f,150.0f,500.0f,1000.0f,400.0f,0.75f,0.05f,0.35f,350.0f,5.0f,0.8f,
                                  0.1f,0.4f,0.2f,0.5f,0.4f,1.0f,6.0f,5.0f};
__device__ const float LOGT[15] = {0.0f,0.69314718f,1.09861229f,1.38629436f,1.60943791f,
                                   1.79175947f,1.94591015f,2.07944154f,2.19722458f,2.30258509f,
                                   2.39789527f,2.48490665f,2.56494936f,2.63905733f,2.70805020f};

__global__ void zero_kernel(float* __restrict__ p, int cnt){
    int i = blockIdx.x*256 + threadIdx.x;
    if (i < cnt) p[i] = 0.0f;
}

// ---------------------------------------------------------------------------
// x-pack: x_dyn [N][T][8] f32 -> xb [N*T] short8 (bf16). Fully parallel.
// ---------------------------------------------------------------------------
__global__ __launch_bounds__(256) void xpack_kernel(
    const float* __restrict__ x_dyn, unsigned short* __restrict__ xb, size_t NT)
{
    size_t i = (size_t)blockIdx.x*256 + threadIdx.x;
    if (i >= NT) return;
    const float4 a = ((const float4*)x_dyn)[2*i];
    const float4 b = ((const float4*)x_dyn)[2*i + 1];
    short8 o;
    o[0]=(short)f2bf(a.x); o[1]=(short)f2bf(a.y); o[2]=(short)f2bf(a.z); o[3]=(short)f2bf(a.w);
    o[4]=(short)f2bf(b.x); o[5]=(short)f2bf(b.y); o[6]=(short)f2bf(b.z); o[7]=(short)f2bf(b.w);
    ((short8*)xb)[i] = o;
}

// ---------------------------------------------------------------------------
// MFMA LSTM (r9 version — measured ~200 us). Raw s_barrier with lgkmcnt-only
// wait keeps the streaming xb load in flight across barriers; x consumed 2
// iterations after issue.
// ---------------------------------------------------------------------------
template<bool XB>
__global__ __launch_bounds__(256, 1) void lstm_kernel(
    const float* __restrict__ x_dyn, const unsigned short* __restrict__ xb,
    const float* __restrict__ x_static,
    const float* __restrict__ Wih, const float* __restrict__ Whh,
    const float* __restrict__ b_lstm, const float* __restrict__ Ws,
    const float* __restrict__ bs, const float* __restrict__ Wout,
    const float* __restrict__ bout, float* __restrict__ params,
    int N, int T, int DSTAT)
{
    __shared__ unsigned short h_lds[2][16*64];
    __shared__ float s_sh[16*64];

    const int tid = threadIdx.x;
    const int wv  = tid >> 6;
    const int ln  = tid & 63;
    const int q   = ln >> 4;
    const int r16 = ln & 15;
    const int u0  = blockIdx.x * 16;

    short8 wf[4][3];
    float  bias[4];
    #pragma unroll
    for (int g = 0; g < 4; ++g) {
        const int n = 64*g + 16*wv + r16;
        bias[g] = b_lstm[n];
        #pragma unroll
        for (int kb = 0; kb < 3; ++kb) {
            short8 w;
            #pragma unroll
            for (int e = 0; e < 8; ++e) {
                int k = 32*kb + 8*q + e;
                float v = 0.0f;
                if (k < 64)      v = Whh[n*64 + k];
                else if (k < 72) v = Wih[n*8 + (k - 64)];
                w[e] = (short)f2bf(v);
            }
            wf[g][kb] = w;
        }
    }

    for (int i = tid; i < 2*16*64; i += 256) ((unsigned short*)h_lds)[i] = 0;
    __syncthreads();

    float c[4] = {0.f, 0.f, 0.f, 0.f};

    const int ux = min(u0 + r16, N-1);
    const int jj   = 16*wv + r16;
    const int swz0 = (q       ^ (r16 & 7)) << 3;
    const int swz1 = ((q + 4) ^ (r16 & 7)) << 3;

#define LSTM_STEP(T_CUR, RB, XREG)                                              \
    {                                                                           \
        short8 a0 = *(const short8*)&h_lds[RB][r16*64 + swz0];                  \
        short8 a1 = *(const short8*)&h_lds[RB][r16*64 + swz1];                  \
        short8 a2 = XREG;                                                       \
        if (q == 0)                                                             \
            XREG = *(const short8*)(xb + ((size_t)ux*T + min((T_CUR)+2, T-1))*8);\
        f32x4 acc[4];                                                           \
        _Pragma("unroll")                                                       \
        for (int gg = 0; gg < 4; ++gg) {                                        \
            f32x4 a; a[0]=bias[gg]; a[1]=bias[gg]; a[2]=bias[gg]; a[3]=bias[gg];\
            a = __builtin_amdgcn_mfma_f32_16x16x32_bf16(a2, wf[gg][2], a,0,0,0);\
            a = __builtin_amdgcn_mfma_f32_16x16x32_bf16(a0, wf[gg][0], a,0,0,0);\
            a = __builtin_amdgcn_mfma_f32_16x16x32_bf16(a1, wf[gg][1], a,0,0,0);\
            acc[gg] = a;                                                        \
        }                                                                       \
        _Pragma("unroll")                                                       \
        for (int r = 0; r < 4; ++r) {                                           \
            float iv = sigf(acc[0][r]);                                         \
            float fv = sigf(acc[1][r]);                                         \
            float gv = tanhfast(acc[2][r]);                                     \
            float ov = sigf(acc[3][r]);                                         \
            c[r] = fv*c[r] + iv*gv;                                             \
            float hv = ov*tanhfast(c[r]);                                       \
            int u = 4*q + r;                                                    \
            h_lds[(RB)^1][u*64 + (((jj>>3) ^ (u&7))<<3) + (jj&7)] = f2bf(hv);   \
        }                                                                       \
        asm volatile("s_waitcnt lgkmcnt(0)" ::: "memory");                      \
        __builtin_amdgcn_s_barrier();                                           \
    }

    if constexpr (XB) {
        short8 x0, x1;
        #pragma unroll
        for (int e = 0; e < 8; ++e) { x0[e] = 0; x1[e] = 0; }
        if (q == 0) {
            x0 = *(const short8*)(xb + ((size_t)ux*T)*8);
            x1 = *(const short8*)(xb + ((size_t)ux*T + min(1, T-1))*8);
        }
        int t = 0;
        for (; t + 1 < T; t += 2) {
            LSTM_STEP(t,   0, x0);
            LSTM_STEP(t+1, 1, x1);
        }
        if (t < T) LSTM_STEP(t, 0, x0);
    } else {
        float xf[8];
        if (q == 0) {
            const float* p = x_dyn + ((size_t)ux * T) * 8;
            #pragma unroll
            for (int e = 0; e < 8; ++e) xf[e] = p[e];
        }
        for (int t = 0; t < T; ++t) {
            short8 a2;
            #pragma unroll
            for (int e = 0; e < 8; ++e) a2[e] = (q == 0) ? (short)f2bf(xf[e]) : (short)0;
            const int rb = t & 1;
            short8 a0 = *(const short8*)&h_lds[rb][r16*64 + swz0];
            short8 a1 = *(const short8*)&h_lds[rb][r16*64 + swz1];
            if (q == 0 && t + 1 < T) {
                const float* p = x_dyn + ((size_t)ux * T + (t+1)) * 8;
                #pragma unroll
                for (int e = 0; e < 8; ++e) xf[e] = p[e];
            }
            f32x4 acc[4];
            #pragma unroll
            for (int g = 0; g < 4; ++g) {
                f32x4 a; a[0]=bias[g]; a[1]=bias[g]; a[2]=bias[g]; a[3]=bias[g];
                a = __builtin_amdgcn_mfma_f32_16x16x32_bf16(a2, wf[g][2], a, 0, 0, 0);
                a = __builtin_amdgcn_mfma_f32_16x16x32_bf16(a0, wf[g][0], a, 0, 0, 0);
                a = __builtin_amdgcn_mfma_f32_16x16x32_bf16(a1, wf[g][1], a, 0, 0, 0);
                acc[g] = a;
            }
            const int wb = rb ^ 1;
            #pragma unroll
            for (int r = 0; r < 4; ++r) {
                float iv = sigf(acc[0][r]);
                float fv = sigf(acc[1][r]);
                float gv = tanhfast(acc[2][r]);
                float ov = sigf(acc[3][r]);
                c[r] = fv*c[r] + iv*gv;
                float hv = ov*tanhfast(c[r]);
                int u = 4*q + r;
                h_lds[wb][u*64 + (((jj>>3) ^ (u&7))<<3) + (jj&7)] = f2bf(hv);
            }
            __syncthreads();
        }
    }
#undef LSTM_STEP

    const int fb = T & 1;
    for (int uu = 0; uu < 4; ++uu) {
        int ul = wv*4 + uu;
        int u  = min(u0 + ul, N-1);
        float a = bs[ln];
        for (int k = 0; k < DSTAT; ++k)
            a = fmaf(x_static[(size_t)u*DSTAT + k], Ws[ln*DSTAT + k], a);
        s_sh[ul*64 + ln] = tanhfast(a);
    }
    if (ln < 30) {
        for (int uu = 0; uu < 4; ++uu) {
            int ul = wv*4 + uu;
            int unit = u0 + ul;
            if (unit < N) {
                float raw = bout[ln];
                #pragma unroll 8
                for (int m = 0; m < 64; ++m) {
                    float hm = bf2f(h_lds[fb][ul*64 + (((m>>3) ^ (ul&7))<<3) + (m&7)]);
                    float sm = s_sh[ul*64 + m];
                    raw = fmaf(hm, Wout[ln*128 + m],      raw);
                    raw = fmaf(sm, Wout[ln*128 + 64 + m], raw);
                }
                float g = sigf(raw);
                params[ln*N + unit] = PLO[ln] + g*(PHI[ln] - PLO[ln]);
            }
        }
    }
}

// ---------------------------------------------------------------------------
// Pack kernel: per (n,t) float4 (prcp, tavg, PET, melt_factor).
// ---------------------------------------------------------------------------
__global__ __launch_bounds__(256) void pack_kernel(
    const float* __restrict__ prcp, const float* __restrict__ tavg,
    const int* __restrict__ doy, const float* __restrict__ lat_rad,
    const float* __restrict__ P,
    float4* __restrict__ pack, int N, int T)
{
    const int n = blockIdx.y;
    const int t = blockIdx.x*256 + threadIdx.x;
    if (t >= T) return;
    const float pr = prcp[(size_t)n*T + t];
    const float ta = tavg[(size_t)n*T + t];
    const float dy = (float)doy[(size_t)n*T + t];
    const float tanlat = __tanf(lat_rad[n]);
    const float HAMON  = P[n];
    const float MFMAX  = P[3*N + n], MFMIN = P[4*N + n];
    float decl  = 0.4093f*__sinf(TWO_PI_365*dy - 1.405f);
    float cosw  = fminf(fmaxf(-tanlat*__tanf(decl), -0.9999f), 0.9999f);
    float daylen= acosf(cosw)*H24_PI;
    float esat  = 0.6108f*__expf(17.27f*ta*frcp(ta + 237.3f));
    float pet   = fmaxf(HAMON*29.8f*daylen*esat*frcp(ta + 273.2f), 0.0f);
    float mf    = 0.5f*(MFMAX + MFMIN) + 0.5f*(MFMAX - MFMIN)*__sinf(TWO_PI_366*dy);
    pack[(size_t)n*T + t] = make_float4(pr, ta, pet, mf);
}

// ---------------------------------------------------------------------------
// Physics serial chain, U=1 (the measured-best configuration: r8 tier0).
// PACKED: one float4 load/t (2-deep prefetch), one float2 store/t.
// ILP-U abandoned: r2/r5/r9 all regressed (state set too large; allocator
// spills the second unit to scratch).
// ---------------------------------------------------------------------------
template<bool PACKED, bool SPLIT>
__global__ __launch_bounds__(64, 1) void physics_kernel(
    const float* __restrict__ prcp, const float* __restrict__ tavg,
    const int*   __restrict__ doy,  const float* __restrict__ elev_m,
    const float* __restrict__ lat_rad, const float* __restrict__ area_w,
    const int*   __restrict__ basin_idx, const float* __restrict__ P,
    const float4* __restrict__ pack, float2* __restrict__ sbA,
    float* __restrict__ surfA, float* __restrict__ baseA,
    float* __restrict__ out, int N, int T, int B)
{
    int n = blockIdx.x*64 + threadIdx.x;
    if (n >= N) return;

    const float HAMON = P[ 0*N+n], SCF   = P[ 1*N+n], PXTEMP= P[ 2*N+n];
    const float MFMAX = P[ 3*N+n], MFMIN = P[ 4*N+n];
    const float MBASE = P[ 6*N+n], TIPM  = P[ 7*N+n], PLWHC = P[ 8*N+n];
    const float NMF   = P[ 9*N+n], DAYGM = P[10*N+n];
    const float UZTWM = P[11*N+n], UZFWM = P[12*N+n], LZTWM = P[13*N+n];
    const float LZFPM = P[14*N+n], LZFSM = P[15*N+n], UZK   = P[16*N+n];
    const float LZPK  = P[17*N+n], LZSK  = P[18*N+n], ZPERC = P[19*N+n];
    const float REXP  = P[20*N+n], PFREE = P[21*N+n], PCTIM = P[22*N+n];
    const float ADIMP = P[23*N+n], SIDE  = P[25*N+n];
    const float UH_N  = P[28*N+n], UH_TAU= P[29*N+n];

    const float mrosk  = P[5*N+n]*__expf(-elev_m[n]*(1.0f/8434.0f))*0.0125f;
    const float tanlat = __tanf(lat_rad[n]);
    const float wA     = area_w[n];
    const int   bi     = basin_idx[n];
    const float mfa = 0.5f*(MFMAX + MFMIN), mfb = 0.5f*(MFMAX - MFMIN);

    float uh[UH_LEN];
    float hist[UH_LEN-1];
    if (!SPLIT) {
        float uhs = 0.0f;
        const float inv_tau = frcp(UH_TAU);
        #pragma unroll
        for (int l = 0; l < UH_LEN; ++l) {
            uh[l] = __expf((UH_N - 1.0f)*LOGT[l] - (float)(l+1)*inv_tau);
            uhs += uh[l];
        }
        float inv_uhs = frcp(uhs);
        #pragma unroll
        for (int l = 0; l < UH_LEN; ++l) uh[l] *= inv_uhs;
        #pragma unroll
        for (int l = 0; l < UH_LEN-1; ++l) hist[l] = 0.0f;
    }

    const float dtq       = 1.0f / (float)N_INC;
    const float kp        = LZPK*dtq, ks = LZSK*dtq, ku = UZK*dtq;
    const float twm_sum   = UZTWM + LZTWM;
    const float inv_uztwm = frcp(UZTWM);
    const float inv_twm   = frcp(twm_sum);
    const float inv_lzmax = frcp(LZTWM + LZFPM + LZFSM);
    const float inv_side  = frcp(1.0f + SIDE);
    const float pinc_fac  = (1.0f - PCTIM - ADIMP)*dtq;
    const float pm        = (LZFPM*LZPK + LZFSM*LZSK)*dtq*frcp(UZFWM);

    float wi = 0.0f, wq = 0.0f, ati = 0.0f;
    float uztwc = 0.5f*UZTWM, uzfwc = 0.5f*UZFWM, lztwc = 0.5f*LZTWM;
    float lzfpc = 0.5f*LZFPM, lzfsc = 0.5f*LZFSM, adimc = 0.5f*twm_sum;

    float* q_gauge = out;
    float* q_base  = out + (size_t)B*T;
    float* q_unit  = out + (size_t)2*B*T;

    const float4* pk = PACKED ? (pack + (size_t)n*T) : nullptr;
    float2*       sb = PACKED ? (sbA  + (size_t)n*T) : nullptr;
    float4 cur, nx1;
    float pr_c, ta_c, pet_c, mf_c;
    if (PACKED) {
        cur = pk[0];
        nx1 = pk[T > 1 ? 1 : 0];
    } else {
        pr_c = prcp[(size_t)n*T];
        ta_c = tavg[(size_t)n*T];
        float dy = (float)doy[(size_t)n*T];
        float decl = 0.4093f*__sinf(TWO_PI_365*dy - 1.405f);
        float cosw = fminf(fmaxf(-tanlat*__tanf(decl), -0.9999f), 0.9999f);
        pet_c = fmaxf(HAMON*29.8f*(acosf(cosw)*H24_PI)
                      *0.6108f*__expf(17.27f*ta_c*frcp(ta_c + 237.3f))
                      *frcp(ta_c + 273.2f), 0.0f);
        mf_c  = mfa + mfb*__sinf(TWO_PI_366*dy);
    }

    for (int t = 0; t < T; ++t) {
        float pr, ta, pet, mf;
        float4 nx2;
        float pr_n, ta_n, dy_n;
        if (PACKED) {
            nx2 = pk[min(t + 2, T - 1)];
            pr = cur.x; ta = cur.y; pet = cur.z; mf = cur.w;
        } else {
            const int tn = min(t + 1, T - 1);
            pr_n = prcp[(size_t)n*T + tn];
            ta_n = tavg[(size_t)n*T + tn];
            dy_n = (float)doy[(size_t)n*T + tn];
            pr = pr_c; ta = ta_c; pet = pet_c; mf = mf_c;
        }

        // --- Snow17 ---
        bool is_snow = (ta <= PXTEMP);
        float ps    = is_snow ? pr*SCF : 0.0f;
        float prain = is_snow ? 0.0f   : pr;
        wi += ps;
        ati += TIPM*(fminf(ta, 0.0f) - ati);
        float mros = mrosk*fmaxf(ta, 0.0f)*((!is_snow && wi > 0.0f) ? prain : 0.0f);
        float melt = fminf(fmaxf(mf*fmaxf(ta - MBASE, 0.0f) + mros - NMF*fmaxf(-ati, 0.0f), 0.0f), wi);
        wi -= melt;
        float gm = fminf(DAYGM, wi);
        wi -= gm;
        float rop   = (wi > 0.0f) ? prain : 0.0f;
        float rfree = prain - rop;
        wq += melt + rop;
        float outq = fmaxf(wq - PLWHC*wi, 0.0f);
        wq -= outq;
        float eff = outq + gm + rfree;

        // --- SAC-SMA ---
        float e1 = fminf(pet*uztwc*inv_uztwm, uztwc);
        uztwc -= e1;
        float red = pet - e1;
        float e2 = fminf(red, uzfwc);
        uzfwc -= e2; red -= e2;
        float e3 = fminf(red*lztwc*inv_twm, lztwc);
        lztwc -= e3;
        float roimp  = eff*PCTIM;
        float padimp = eff*ADIMP;
        adimc += padimp;
        float ratio = fminf(fmaxf(adimc*inv_twm, 0.0f), 1.0f);
        float adsur = padimp*ratio*ratio;
        adimc = fminf(adimc - adsur, twm_sum);
        float surf = roimp + adsur;
        float base = 0.0f;
        float pinc = eff*pinc_fac;
        #pragma unroll
        for (int inc = 0; inc < N_INC; ++inc) {
            float bfp = lzfpc*kp;
            float bfs = lzfsc*ks;
            lzfpc -= bfp; lzfsc -= bfs;
            base += (bfp + bfs)*inv_side;
            float qif = uzfwc*ku;
            uzfwc -= qif; surf += qif;
            float lz_def = (LZTWM - lztwc) + (LZFPM - lzfpc) + (LZFSM - lzfsc);
            float defr = fminf(fmaxf(lz_def*inv_lzmax, 1e-6f), 1.0f);
            float perc = pm*fmaf(ZPERC, __expf(REXP*__logf(defr)), 1.0f)*uzfwc;
            perc = fminf(fminf(perc, uzfwc), fmaxf(lz_def, 0.0f));
            uzfwc -= perc;
            float pfree = perc*PFREE;
            lztwc += perc - pfree;
            float ex = fmaxf(lztwc - LZTWM, 0.0f);
            lztwc -= ex; pfree += ex;
            float dp  = fmaxf(LZFPM - lzfpc, 0.0f);
            float dsx = fmaxf(LZFSM - lzfsc, 0.0f);
            float fr  = dp*frcp(fmaxf(dp + dsx, 1e-6f));
            lzfpc += pfree*fr;
            lzfsc += pfree*(1.0f - fr);
            float exq = fmaxf(lzfpc - LZFPM, 0.0f);
            lzfpc -= exq; lzfsc += exq;
            float exs = fmaxf(lzfsc - LZFSM, 0.0f);
            lzfsc -= exs; surf += exs;
            uztwc += pinc;
            float exu = fmaxf(uztwc - UZTWM, 0.0f);
            uztwc -= exu; uzfwc += exu;
            float exf = fmaxf(uzfwc - UZFWM, 0.0f);
            uzfwc -= exf; surf += exf;
        }

        if (PACKED) {
            sb[t] = make_float2(surf, base);
            cur = nx1; nx1 = nx2;
        } else if (SPLIT) {
            surfA[(size_t)n*T + t] = surf;
            baseA[(size_t)n*T + t] = base;
        } else {
            float qv = uh[0]*surf;
            #pragma unroll
            for (int l = 1; l < UH_LEN; ++l) qv = fmaf(uh[l], hist[l-1], qv);
            #pragma unroll
            for (int l = UH_LEN-2; l >= 1; --l) hist[l] = hist[l-1];
            hist[0] = surf;
            qv += base;
            q_unit[(size_t)n*T + t] = qv;
            atomicAdd(&q_gauge[(size_t)bi*T + t], qv*wA);
            atomicAdd(&q_base [(size_t)bi*T + t], base*wA);
        }

        if (!PACKED) {
            float decl = 0.4093f*__sinf(TWO_PI_365*dy_n - 1.405f);
            float cosw = fminf(fmaxf(-tanlat*__tanf(decl), -0.9999f), 0.9999f);
            pet_c = fmaxf(HAMON*29.8f*(acosf(cosw)*H24_PI)
                          *0.6108f*__expf(17.27f*ta_n*frcp(ta_n + 237.3f))
                          *frcp(ta_n + 273.2f), 0.0f);
            mf_c = mfa + mfb*__sinf(TWO_PI_366*dy_n);
            pr_c = pr_n; ta_c = ta_n;
        }
    }
}

// ---------------------------------------------------------------------------
// Routing + gauge segment-sum: fully parallel over (n, t).
// ---------------------------------------------------------------------------
template<bool PACKED>
__global__ __launch_bounds__(256) void route_kernel(
    const float2* __restrict__ sbA,
    const float* __restrict__ surfA, const float* __restrict__ baseA,
    const float* __restrict__ P, const float* __restrict__ area_w,
    const int* __restrict__ basin_idx,
    float* __restrict__ out, int N, int T, int B)
{
    __shared__ float uh_sh[UH_LEN];
    __shared__ float wA_sh;
    __shared__ int   bi_sh;

    const int n = blockIdx.y;
    const int t = blockIdx.x*256 + threadIdx.x;

    if (threadIdx.x == 0) {
        float UH_N = P[28*N + n], UH_TAU = P[29*N + n];
        float inv_tau = frcp(UH_TAU);
        float tmp[UH_LEN], s = 0.f;
        #pragma unroll
        for (int l = 0; l < UH_LEN; ++l) {
            tmp[l] = __expf((UH_N - 1.0f)*LOGT[l] - (float)(l+1)*inv_tau);
            s += tmp[l];
        }
        float is = frcp(s);
        #pragma unroll
        for (int l = 0; l < UH_LEN; ++l) uh_sh[l] = tmp[l]*is;
        wA_sh = area_w[n];
        bi_sh = basin_idx[n];
    }
    __syncthreads();
    if (t >= T) return;

    float base, acc = 0.f;
    if (PACKED) {
        const float2* sb = sbA + (size_t)n*T;
        base = sb[t].y;
        #pragma unroll
        for (int l = 0; l < UH_LEN; ++l) {
            int tt = t - l;
            if (tt >= 0) acc = fmaf(uh_sh[l], sb[tt].x, acc);
        }
    } else {
        base = baseA[(size_t)n*T + t];
        #pragma unroll
        for (int l = 0; l < UH_LEN; ++l) {
            int tt = t - l;
            if (tt >= 0) acc = fmaf(uh_sh[l], surfA[(size_t)n*T + tt], acc);
        }
    }
    const float qv = acc + base;

    float* q_gauge = out;
    float* q_base  = out + (size_t)B*T;
    float* q_unit  = out + (size_t)2*B*T;

    q_unit[(size_t)n*T + t] = qv;
    atomicAdd(&q_gauge[(size_t)bi_sh*T + t], qv*wA_sh);
    atomicAdd(&q_base [(size_t)bi_sh*T + t], base*wA_sh);
}

static inline size_t align256(size_t x){ return (x + 255) & ~(size_t)255; }

extern "C" void kernel_launch(void* const* d_in, const int* in_sizes, int n_in,
                              void* d_out, int out_size, void* d_ws, size_t ws_size,
                              hipStream_t stream) {
    const float* x_dyn    = (const float*)d_in[0];
    const float* x_static = (const float*)d_in[1];
    const float* prcp     = (const float*)d_in[2];
    const float* tavg     = (const float*)d_in[3];
    const int*   doy      = (const int*)  d_in[4];
    const float* elev_m   = (const float*)d_in[5];
    const float* lat_rad  = (const float*)d_in[6];
    const float* area_w   = (const float*)d_in[7];
    const int*   basin_ix = (const int*)  d_in[8];
    const float* Wih      = (const float*)d_in[10];
    const float* Whh      = (const float*)d_in[11];
    const float* b_lstm   = (const float*)d_in[12];
    const float* Ws       = (const float*)d_in[13];
    const float* bs       = (const float*)d_in[14];
    const float* Wout     = (const float*)d_in[15];
    const float* bout     = (const float*)d_in[16];

    const int N = in_sizes[7];
    const int T = in_sizes[2] / N;
    const int DSTAT = in_sizes[1] / N;
    const size_t NT = (size_t)N * T;
    const int B = (out_size - (int)NT) / (2 * T);

    char* wsb = (char*)d_ws;
    float* params = (float*)wsb;
    const size_t off_prm = align256(30*(size_t)N*sizeof(float));

    // tier0: params | xb(16NT) | pack(16NT) | sb(8NT)
    const size_t off_xb0   = off_prm;
    const size_t off_pack0 = align256(off_xb0 + NT*16);
    const size_t off_sb0   = align256(off_pack0 + NT*16);
    const size_t need0     = off_sb0 + NT*8;
    // tier1: params | pack | sb (no xb)
    const size_t off_pack1 = off_prm;
    const size_t off_sb1   = align256(off_pack1 + NT*16);
    const size_t need1     = off_sb1 + NT*8;
    // tier2: params | surf | base
    const size_t off_surf2 = off_prm;
    const size_t off_base2 = off_surf2 + NT*4;
    const size_t need2     = off_base2 + NT*4;

    const int tier = (ws_size >= need0) ? 0 : (ws_size >= need1) ? 1 :
                     (ws_size >= need2) ? 2 : 3;

    float* out = (float*)d_out;
    const int zc = 2 * B * T;
    zero_kernel<<<(zc + 255)/256, 256, 0, stream>>>(out, zc);

    const int blocks_lstm = (N + 15) / 16;
    const int pblocks = (N + 63) / 64;
    dim3 rg((T + 255)/256, N);

    if (tier == 0) {
        unsigned short* xbp = (unsigned short*)(wsb + off_xb0);
        float4* pack = (float4*)(wsb + off_pack0);
        float2* sbA  = (float2*)(wsb + off_sb0);
        xpack_kernel<<<(int)((NT + 255)/256), 256, 0, stream>>>(x_dyn, xbp, NT);
        lstm_kernel<true><<<blocks_lstm, 256, 0, stream>>>(
            x_dyn, xbp, x_static, Wih, Whh, b_lstm, Ws, bs, Wout, bout,
            params, N, T, DSTAT);
        pack_kernel<<<rg, 256, 0, stream>>>(prcp, tavg, doy, lat_rad, params, pack, N, T);
        physics_kernel<true, true><<<pblocks, 64, 0, stream>>>(
            prcp, tavg, doy, elev_m, lat_rad, area_w, basin_ix, params,
            pack, sbA, nullptr, nullptr, out, N, T, B);
        route_kernel<true><<<rg, 256, 0, stream>>>(sbA, nullptr, nullptr, params, area_w,
                                                   basin_ix, out, N, T, B);
    } else if (tier == 1) {
        float4* pack = (float4*)(wsb + off_pack1);
        float2* sbA  = (float2*)(wsb + off_sb1);
        lstm_kernel<false><<<blocks_lstm, 256, 0, stream>>>(
            x_dyn, nullptr, x_static, Wih, Whh, b_lstm, Ws, bs, Wout, bout,
            params, N, T, DSTAT);
        pack_kernel<<<rg, 256, 0, stream>>>(prcp, tavg, doy, lat_rad, params, pack, N, T);
        physics_kernel<true, true><<<pblocks, 64, 0, stream>>>(
            prcp, tavg, doy, elev_m, lat_rad, area_w, basin_ix, params,
            pack, sbA, nullptr, nullptr, out, N, T, B);
        route_kernel<true><<<rg, 256, 0, stream>>>(sbA, nullptr, nullptr, params, area_w,
                                                   basin_ix, out, N, T, B);
    } else if (tier == 2) {
        float* surfA = (float*)(wsb + off_surf2);
        float* baseA = (float*)(wsb + off_base2);
        lstm_kernel<false><<<blocks_lstm, 256, 0, stream>>>(
            x_dyn, nullptr, x_static, Wih, Whh, b_lstm, Ws, bs, Wout, bout,
            params, N, T, DSTAT);
        physics_kernel<false, true><<<pblocks, 64, 0, stream>>>(
            prcp, tavg, doy, elev_m, lat_rad, area_w, basin_ix, params,
            nullptr, nullptr, surfA, baseA, out, N, T, B);
        route_kernel<false><<<rg, 256, 0, stream>>>(nullptr, surfA, baseA, params, area_w,
                                                    basin_ix, out, N, T, B);
    } else {
        lstm_kernel<false><<<blocks_lstm, 256, 0, stream>>>(
            x_dyn, nullptr, x_static, Wih, Whh, b_lstm, Ws, bs, Wout, bout,
            params, N, T, DSTAT);
        physics_kernel<false, false><<<pblocks, 64, 0, stream>>>(
            prcp, tavg, doy, elev_m, lat_rad, area_w, basin_ix, params,
            nullptr, nullptr, nullptr, nullptr, out, N, T, B);
    }
}

// Round 11
// 1042.869 us; speedup vs baseline: 1.5742x; 1.0200x over previous
//
#include <hip/hip_runtime.h>
#include <math.h>

#define HID 64
#define UH_LEN 15
#define N_INC 4

#define TWO_PI_365 0.0172142063f
#define TWO_PI_366 0.0171671554f
#define H24_PI     7.63943727f

typedef short short8 __attribute__((ext_vector_type(8)));
typedef float f32x4  __attribute__((ext_vector_type(4)));

__device__ __forceinline__ float frcp(float x){ return __builtin_amdgcn_rcpf(x); }
__device__ __forceinline__ float sigf(float x){ return frcp(1.0f + __expf(-x)); }
__device__ __forceinline__ float tanhfast(float x){ return 1.0f - 2.0f*frcp(__expf(2.0f*x)+1.0f); }

__device__ __forceinline__ unsigned short f2bf(float f){
    unsigned int u = __float_as_uint(f);
    u += 0x7FFF + ((u >> 16) & 1);
    return (unsigned short)(u >> 16);
}
__device__ __forceinline__ float bf2f(unsigned short h){
    return __uint_as_float(((unsigned int)h) << 16);
}

__device__ const float PLO[30] = {0.5f,0.7f,-2.0f,0.5f,0.05f,0.03f,0.0f,0.1f,0.02f,0.05f,0.0f,
                                  10.0f,5.0f,10.0f,10.0f,5.0f,0.1f,0.001f,0.01f,5.0f,1.0f,0.0f,
                                  0.0f,0.0f,0.0f,0.0f,0.0f,0.0f,1.0f,0.5f};
__device__ const float PHI[30] = {2.0f,1.4f,2.0f,2.0f,0.49f,0.19f,1.0f,1.0f,0.3f,0.5f,0.3f,
                                  300.0f,150.0f,500.0f,1000.0f,400.0f,0.75f,0.05f,0.35f,350.0f,5.0f,0.8f,
                                  0.1f,0.4f,0.2f,0.5f,0.4f,1.0f,6.0f,5.0f};
__device__ const float LOGT[15] = {0.0f,0.69314718f,1.09861229f,1.38629436f,1.60943791f,
                                   1.79175947f,1.94591015f,2.07944154f,2.19722458f,2.30258509f,
                                   2.39789527f,2.48490665f,2.56494936f,2.63905733f,2.70805020f};

__global__ void zero_kernel(float* __restrict__ p, int cnt){
    int i = blockIdx.x*256 + threadIdx.x;
    if (i < cnt) p[i] = 0.0f;
}

// ---------------------------------------------------------------------------
// x-pack: x_dyn [N][T][8] f32 -> xb [N*T] short8 (bf16). Fully parallel.
// ---------------------------------------------------------------------------
__global__ __launch_bounds__(256) void xpack_kernel(
    const float* __restrict__ x_dyn, unsigned short* __restrict__ xb, size_t NT)
{
    size_t i = (size_t)blockIdx.x*256 + threadIdx.x;
    if (i >= NT) return;
    const float4 a = ((const float4*)x_dyn)[2*i];
    const float4 b = ((const float4*)x_dyn)[2*i + 1];
    short8 o;
    o[0]=(short)f2bf(a.x); o[1]=(short)f2bf(a.y); o[2]=(short)f2bf(a.z); o[3]=(short)f2bf(a.w);
    o[4]=(short)f2bf(b.x); o[5]=(short)f2bf(b.y); o[6]=(short)f2bf(b.z); o[7]=(short)f2bf(b.w);
    ((short8*)xb)[i] = o;
}

// ---------------------------------------------------------------------------
// MFMA LSTM (r9 version — measured ~200 us). Raw s_barrier with lgkmcnt-only
// wait keeps the streaming xb load in flight across barriers.
// ---------------------------------------------------------------------------
template<bool XB>
__global__ __launch_bounds__(256, 1) void lstm_kernel(
    const float* __restrict__ x_dyn, const unsigned short* __restrict__ xb,
    const float* __restrict__ x_static,
    const float* __restrict__ Wih, const float* __restrict__ Whh,
    const float* __restrict__ b_lstm, const float* __restrict__ Ws,
    const float* __restrict__ bs, const float* __restrict__ Wout,
    const float* __restrict__ bout, float* __restrict__ params,
    int N, int T, int DSTAT)
{
    __shared__ unsigned short h_lds[2][16*64];
    __shared__ float s_sh[16*64];

    const int tid = threadIdx.x;
    const int wv  = tid >> 6;
    const int ln  = tid & 63;
    const int q   = ln >> 4;
    const int r16 = ln & 15;
    const int u0  = blockIdx.x * 16;

    short8 wf[4][3];
    float  bias[4];
    #pragma unroll
    for (int g = 0; g < 4; ++g) {
        const int n = 64*g + 16*wv + r16;
        bias[g] = b_lstm[n];
        #pragma unroll
        for (int kb = 0; kb < 3; ++kb) {
            short8 w;
            #pragma unroll
            for (int e = 0; e < 8; ++e) {
                int k = 32*kb + 8*q + e;
                float v = 0.0f;
                if (k < 64)      v = Whh[n*64 + k];
                else if (k < 72) v = Wih[n*8 + (k - 64)];
                w[e] = (short)f2bf(v);
            }
            wf[g][kb] = w;
        }
    }

    for (int i = tid; i < 2*16*64; i += 256) ((unsigned short*)h_lds)[i] = 0;
    __syncthreads();

    float c[4] = {0.f, 0.f, 0.f, 0.f};

    const int ux = min(u0 + r16, N-1);
    const int jj   = 16*wv + r16;
    const int swz0 = (q       ^ (r16 & 7)) << 3;
    const int swz1 = ((q + 4) ^ (r16 & 7)) << 3;

#define LSTM_STEP(T_CUR, RB, XREG)                                              \
    {                                                                           \
        short8 a0 = *(const short8*)&h_lds[RB][r16*64 + swz0];                  \
        short8 a1 = *(const short8*)&h_lds[RB][r16*64 + swz1];                  \
        short8 a2 = XREG;                                                       \
        if (q == 0)                                                             \
            XREG = *(const short8*)(xb + ((size_t)ux*T + min((T_CUR)+2, T-1))*8);\
        f32x4 acc[4];                                                           \
        _Pragma("unroll")                                                       \
        for (int gg = 0; gg < 4; ++gg) {                                        \
            f32x4 a; a[0]=bias[gg]; a[1]=bias[gg]; a[2]=bias[gg]; a[3]=bias[gg];\
            a = __builtin_amdgcn_mfma_f32_16x16x32_bf16(a2, wf[gg][2], a,0,0,0);\
            a = __builtin_amdgcn_mfma_f32_16x16x32_bf16(a0, wf[gg][0], a,0,0,0);\
            a = __builtin_amdgcn_mfma_f32_16x16x32_bf16(a1, wf[gg][1], a,0,0,0);\
            acc[gg] = a;                                                        \
        }                                                                       \
        _Pragma("unroll")                                                       \
        for (int r = 0; r < 4; ++r) {                                           \
            float iv = sigf(acc[0][r]);                                         \
            float fv = sigf(acc[1][r]);                                         \
            float gv = tanhfast(acc[2][r]);                                     \
            float ov = sigf(acc[3][r]);                                         \
            c[r] = fv*c[r] + iv*gv;                                             \
            float hv = ov*tanhfast(c[r]);                                       \
            int u = 4*q + r;                                                    \
            h_lds[(RB)^1][u*64 + (((jj>>3) ^ (u&7))<<3) + (jj&7)] = f2bf(hv);   \
        }                                                                       \
        asm volatile("s_waitcnt lgkmcnt(0)" ::: "memory");                      \
        __builtin_amdgcn_s_barrier();                                           \
    }

    if constexpr (XB) {
        short8 x0, x1;
        #pragma unroll
        for (int e = 0; e < 8; ++e) { x0[e] = 0; x1[e] = 0; }
        if (q == 0) {
            x0 = *(const short8*)(xb + ((size_t)ux*T)*8);
            x1 = *(const short8*)(xb + ((size_t)ux*T + min(1, T-1))*8);
        }
        int t = 0;
        for (; t + 1 < T; t += 2) {
            LSTM_STEP(t,   0, x0);
            LSTM_STEP(t+1, 1, x1);
        }
        if (t < T) LSTM_STEP(t, 0, x0);
    } else {
        float xf[8];
        if (q == 0) {
            const float* p = x_dyn + ((size_t)ux * T) * 8;
            #pragma unroll
            for (int e = 0; e < 8; ++e) xf[e] = p[e];
        }
        for (int t = 0; t < T; ++t) {
            short8 a2;
            #pragma unroll
            for (int e = 0; e < 8; ++e) a2[e] = (q == 0) ? (short)f2bf(xf[e]) : (short)0;
            const int rb = t & 1;
            short8 a0 = *(const short8*)&h_lds[rb][r16*64 + swz0];
            short8 a1 = *(const short8*)&h_lds[rb][r16*64 + swz1];
            if (q == 0 && t + 1 < T) {
                const float* p = x_dyn + ((size_t)ux * T + (t+1)) * 8;
                #pragma unroll
                for (int e = 0; e < 8; ++e) xf[e] = p[e];
            }
            f32x4 acc[4];
            #pragma unroll
            for (int g = 0; g < 4; ++g) {
                f32x4 a; a[0]=bias[g]; a[1]=bias[g]; a[2]=bias[g]; a[3]=bias[g];
                a = __builtin_amdgcn_mfma_f32_16x16x32_bf16(a2, wf[g][2], a, 0, 0, 0);
                a = __builtin_amdgcn_mfma_f32_16x16x32_bf16(a0, wf[g][0], a, 0, 0, 0);
                a = __builtin_amdgcn_mfma_f32_16x16x32_bf16(a1, wf[g][1], a, 0, 0, 0);
                acc[g] = a;
            }
            const int wb = rb ^ 1;
            #pragma unroll
            for (int r = 0; r < 4; ++r) {
                float iv = sigf(acc[0][r]);
                float fv = sigf(acc[1][r]);
                float gv = tanhfast(acc[2][r]);
                float ov = sigf(acc[3][r]);
                c[r] = fv*c[r] + iv*gv;
                float hv = ov*tanhfast(c[r]);
                int u = 4*q + r;
                h_lds[wb][u*64 + (((jj>>3) ^ (u&7))<<3) + (jj&7)] = f2bf(hv);
            }
            __syncthreads();
        }
    }
#undef LSTM_STEP

    const int fb = T & 1;
    for (int uu = 0; uu < 4; ++uu) {
        int ul = wv*4 + uu;
        int u  = min(u0 + ul, N-1);
        float a = bs[ln];
        for (int k = 0; k < DSTAT; ++k)
            a = fmaf(x_static[(size_t)u*DSTAT + k], Ws[ln*DSTAT + k], a);
        s_sh[ul*64 + ln] = tanhfast(a);
    }
    if (ln < 30) {
        for (int uu = 0; uu < 4; ++uu) {
            int ul = wv*4 + uu;
            int unit = u0 + ul;
            if (unit < N) {
                float raw = bout[ln];
                #pragma unroll 8
                for (int m = 0; m < 64; ++m) {
                    float hm = bf2f(h_lds[fb][ul*64 + (((m>>3) ^ (ul&7))<<3) + (m&7)]);
                    float sm = s_sh[ul*64 + m];
                    raw = fmaf(hm, Wout[ln*128 + m],      raw);
                    raw = fmaf(sm, Wout[ln*128 + 64 + m], raw);
                }
                float g = sigf(raw);
                params[ln*N + unit] = PLO[ln] + g*(PHI[ln] - PLO[ln]);
            }
        }
    }
}

// ---------------------------------------------------------------------------
// Pack kernel: per (n,t) float4 (prcp, tavg, PET, melt_factor).
// ---------------------------------------------------------------------------
__global__ __launch_bounds__(256) void pack_kernel(
    const float* __restrict__ prcp, const float* __restrict__ tavg,
    const int* __restrict__ doy, const float* __restrict__ lat_rad,
    const float* __restrict__ P,
    float4* __restrict__ pack, int N, int T)
{
    const int n = blockIdx.y;
    const int t = blockIdx.x*256 + threadIdx.x;
    if (t >= T) return;
    const float pr = prcp[(size_t)n*T + t];
    const float ta = tavg[(size_t)n*T + t];
    const float dy = (float)doy[(size_t)n*T + t];
    const float tanlat = __tanf(lat_rad[n]);
    const float HAMON  = P[n];
    const float MFMAX  = P[3*N + n], MFMIN = P[4*N + n];
    float decl  = 0.4093f*__sinf(TWO_PI_365*dy - 1.405f);
    float cosw  = fminf(fmaxf(-tanlat*__tanf(decl), -0.9999f), 0.9999f);
    float daylen= acosf(cosw)*H24_PI;
    float esat  = 0.6108f*__expf(17.27f*ta*frcp(ta + 237.3f));
    float pet   = fmaxf(HAMON*29.8f*daylen*esat*frcp(ta + 273.2f), 0.0f);
    float mf    = 0.5f*(MFMAX + MFMIN) + 0.5f*(MFMAX - MFMIN)*__sinf(TWO_PI_366*dy);
    pack[(size_t)n*T + t] = make_float4(pr, ta, pet, mf);
}

// ---------------------------------------------------------------------------
// Physics FAST (tier0/1): chain-restructured. Every subtract-excess pattern
// becomes a parallel {min, max} pair; decays folded to single muls with
// precomputed (1-k); evap head and all input-only terms hoisted off-chain.
// Semantics identical up to mul-reassociation rounding.
// ---------------------------------------------------------------------------
__global__ __launch_bounds__(64, 1) void physics_fast_kernel(
    const float* __restrict__ elev_m, const float* __restrict__ P,
    const float4* __restrict__ pack, float2* __restrict__ sbA, int N, int T)
{
    int n = blockIdx.x*64 + threadIdx.x;
    if (n >= N) return;

    const float SCF   = P[ 1*N+n], PXTEMP= P[ 2*N+n];
    const float MBASE = P[ 6*N+n], TIPM  = P[ 7*N+n], PLWHC = P[ 8*N+n];
    const float NMF   = P[ 9*N+n], DAYGM = P[10*N+n];
    const float UZTWM = P[11*N+n], UZFWM = P[12*N+n], LZTWM = P[13*N+n];
    const float LZFPM = P[14*N+n], LZFSM = P[15*N+n];
    const float UZK   = P[16*N+n], LZPK  = P[17*N+n], LZSK  = P[18*N+n];
    const float ZPERC = P[19*N+n], REXP  = P[20*N+n], PFREE = P[21*N+n];
    const float PCTIM = P[22*N+n], ADIMP = P[23*N+n], SIDE  = P[25*N+n];

    const float mrosk = P[5*N+n]*__expf(-elev_m[n]*(1.0f/8434.0f))*0.0125f;
    const float dtq   = 1.0f/(float)N_INC;
    const float kp = LZPK*dtq, ks = LZSK*dtq, ku = UZK*dtq;
    const float c1p = 1.f-kp, c1s = 1.f-ks, c1u = 1.f-ku, c1t = 1.f-TIPM;
    const float twm = UZTWM + LZTWM;
    const float iUZTWM = frcp(UZTWM), itwm = frcp(twm);
    const float lzmax  = LZTWM + LZFPM + LZFSM;
    const float ilzmax = frcp(lzmax);
    const float iside  = frcp(1.f + SIDE);
    const float pfac   = (1.f - PCTIM - ADIMP)*dtq;
    const float pm     = (LZFPM*LZPK + LZFSM*LZSK)*dtq*frcp(UZFWM);

    float wi = 0.f, wq = 0.f, ati = 0.f;
    float uztwc = .5f*UZTWM, uzfwc = .5f*UZFWM, lztwc = .5f*LZTWM;
    float lzfpc = .5f*LZFPM, lzfsc = .5f*LZFSM, adimc = .5f*twm;

    const float4* pk = pack + (size_t)n*T;
    float2*       sb = sbA  + (size_t)n*T;
    float4 cur = pk[0];
    float4 nx1 = pk[T > 1 ? 1 : 0];

    for (int t = 0; t < T; ++t) {
        float4 nx2 = pk[min(t + 2, T - 1)];
        const float pr = cur.x, ta = cur.y, pet = cur.z, mf = cur.w;

        // ---- off-chain precompute (inputs/params only) ----
        const bool  is_snow = (ta <= PXTEMP);
        const float ps    = is_snow ? pr*SCF : 0.f;
        const float prain = is_snow ? 0.f : pr;
        const float tmros = mrosk*fmaxf(ta, 0.f)*prain;
        const float m0    = mf*fmaxf(ta - MBASE, 0.f);
        const float atia  = TIPM*fminf(ta, 0.f);
        const float me1   = fminf(pet*iUZTWM, 1.f);
        const float e1fac = 1.f - me1;

        // ---- Snow17 chain ----
        ati = c1t*ati + atia;
        float wi1  = wi + ps;
        float mros = (!is_snow && wi1 > 0.f) ? tmros : 0.f;
        float melt = fminf(fmaxf(m0 + mros - NMF*fmaxf(-ati, 0.f), 0.f), wi1);
        float wi2  = wi1 - melt;
        float gm   = fminf(DAYGM, wi2);
        float wi3  = fmaxf(wi2 - DAYGM, 0.f);
        wi = wi3;
        float rop   = (wi3 > 0.f) ? prain : 0.f;
        float rfree = prain - rop;
        float wq1 = wq + melt + rop;
        float cap = PLWHC*wi3;
        float outq = fmaxf(wq1 - cap, 0.f);
        wq = fminf(wq1, cap);
        float eff = outq + gm + rfree;

        // ---- SAC-SMA evap (folded) ----
        float red  = pet - uztwc*me1;           // red = pet - e1
        uztwc = uztwc*e1fac;
        float red2 = fmaxf(red - uzfwc, 0.f);   // residual after e2 (old uzfwc)
        uzfwc = fmaxf(uzfwc - red, 0.f);
        lztwc = lztwc*(1.f - fminf(red2*itwm, 1.f));

        float roimp  = eff*PCTIM;
        float padimp = eff*ADIMP;
        float adimc1 = adimc + padimp;
        float ratio  = fminf(fmaxf(adimc1*itwm, 0.f), 1.f);
        float adsur  = padimp*ratio*ratio;
        adimc = fminf(adimc1 - adsur, twm);
        float surf = roimp + adsur;
        float base = 0.f;
        float pinc = eff*pfac;

        #pragma unroll
        for (int inc = 0; inc < N_INC; ++inc) {
            float bfp = lzfpc*kp, bfs = lzfsc*ks;
            lzfpc *= c1p; lzfsc *= c1s;
            base += (bfp + bfs)*iside;
            float qif = uzfwc*ku;
            uzfwc *= c1u;
            surf += qif;
            float lz_def = lzmax - (lztwc + (lzfpc + lzfsc));
            float defr = fminf(fmaxf(lz_def*ilzmax, 1e-6f), 1.f);
            float perc = pm*fmaf(ZPERC, __expf(REXP*__logf(defr)), 1.f)*uzfwc;
            perc = fminf(fminf(perc, uzfwc), fmaxf(lz_def, 0.f));
            uzfwc -= perc;
            float pfree0 = perc*PFREE;
            float lztwc1 = lztwc + perc - pfree0;
            float ex = fmaxf(lztwc1 - LZTWM, 0.f);
            lztwc = fminf(lztwc1, LZTWM);
            float pfree = pfree0 + ex;
            float dp  = fmaxf(LZFPM - lzfpc, 0.f);
            float dsx = fmaxf(LZFSM - lzfsc, 0.f);
            float fr  = dp*frcp(fmaxf(dp + dsx, 1e-6f));
            float lzfpc1 = lzfpc + pfree*fr;
            float lzfsc1 = lzfsc + pfree*(1.f - fr);
            float exq = fmaxf(lzfpc1 - LZFPM, 0.f);
            lzfpc = fminf(lzfpc1, LZFPM);
            float lzfsc2 = lzfsc1 + exq;
            float exs = fmaxf(lzfsc2 - LZFSM, 0.f);
            lzfsc = fminf(lzfsc2, LZFSM);
            surf += exs;
            float uztwc1 = uztwc + pinc;
            float exu = fmaxf(uztwc1 - UZTWM, 0.f);
            uztwc = fminf(uztwc1, UZTWM);
            float uzfwc1 = uzfwc + exu;
            float exf = fmaxf(uzfwc1 - UZFWM, 0.f);
            uzfwc = fminf(uzfwc1, UZFWM);
            surf += exf;
        }

        sb[t] = make_float2(surf, base);
        cur = nx1; nx1 = nx2;
    }
}

// ---------------------------------------------------------------------------
// Physics fallback (tiers 2/3): proven r8/r10 body, unchanged.
// ---------------------------------------------------------------------------
template<bool SPLIT>
__global__ __launch_bounds__(64, 1) void physics_kernel(
    const float* __restrict__ prcp, const float* __restrict__ tavg,
    const int*   __restrict__ doy,  const float* __restrict__ elev_m,
    const float* __restrict__ lat_rad, const float* __restrict__ area_w,
    const int*   __restrict__ basin_idx, const float* __restrict__ P,
    float* __restrict__ surfA, float* __restrict__ baseA,
    float* __restrict__ out, int N, int T, int B)
{
    int n = blockIdx.x*64 + threadIdx.x;
    if (n >= N) return;

    const float HAMON = P[ 0*N+n], SCF   = P[ 1*N+n], PXTEMP= P[ 2*N+n];
    const float MFMAX = P[ 3*N+n], MFMIN = P[ 4*N+n];
    const float MBASE = P[ 6*N+n], TIPM  = P[ 7*N+n], PLWHC = P[ 8*N+n];
    const float NMF   = P[ 9*N+n], DAYGM = P[10*N+n];
    const float UZTWM = P[11*N+n], UZFWM = P[12*N+n], LZTWM = P[13*N+n];
    const float LZFPM = P[14*N+n], LZFSM = P[15*N+n], UZK   = P[16*N+n];
    const float LZPK  = P[17*N+n], LZSK  = P[18*N+n], ZPERC = P[19*N+n];
    const float REXP  = P[20*N+n], PFREE = P[21*N+n], PCTIM = P[22*N+n];
    const float ADIMP = P[23*N+n], SIDE  = P[25*N+n];
    const float UH_N  = P[28*N+n], UH_TAU= P[29*N+n];

    const float mrosk  = P[5*N+n]*__expf(-elev_m[n]*(1.0f/8434.0f))*0.0125f;
    const float tanlat = __tanf(lat_rad[n]);
    const float wA     = area_w[n];
    const int   bi     = basin_idx[n];
    const float mfa = 0.5f*(MFMAX + MFMIN), mfb = 0.5f*(MFMAX - MFMIN);

    float uh[UH_LEN];
    float hist[UH_LEN-1];
    if (!SPLIT) {
        float uhs = 0.0f;
        const float inv_tau = frcp(UH_TAU);
        #pragma unroll
        for (int l = 0; l < UH_LEN; ++l) {
            uh[l] = __expf((UH_N - 1.0f)*LOGT[l] - (float)(l+1)*inv_tau);
            uhs += uh[l];
        }
        float inv_uhs = frcp(uhs);
        #pragma unroll
        for (int l = 0; l < UH_LEN; ++l) uh[l] *= inv_uhs;
        #pragma unroll
        for (int l = 0; l < UH_LEN-1; ++l) hist[l] = 0.0f;
    }

    const float dtq       = 1.0f / (float)N_INC;
    const float kp        = LZPK*dtq, ks = LZSK*dtq, ku = UZK*dtq;
    const float twm_sum   = UZTWM + LZTWM;
    const float inv_uztwm = frcp(UZTWM);
    const float inv_twm   = frcp(twm_sum);
    const float inv_lzmax = frcp(LZTWM + LZFPM + LZFSM);
    const float inv_side  = frcp(1.0f + SIDE);
    const float pinc_fac  = (1.0f - PCTIM - ADIMP)*dtq;
    const float pm        = (LZFPM*LZPK + LZFSM*LZSK)*dtq*frcp(UZFWM);

    float wi = 0.0f, wq = 0.0f, ati = 0.0f;
    float uztwc = 0.5f*UZTWM, uzfwc = 0.5f*UZFWM, lztwc = 0.5f*LZTWM;
    float lzfpc = 0.5f*LZFPM, lzfsc = 0.5f*LZFSM, adimc = 0.5f*twm_sum;

    float* q_gauge = out;
    float* q_base  = out + (size_t)B*T;
    float* q_unit  = out + (size_t)2*B*T;

    float pr_c = prcp[(size_t)n*T];
    float ta_c = tavg[(size_t)n*T];
    float dy0 = (float)doy[(size_t)n*T];
    float decl0 = 0.4093f*__sinf(TWO_PI_365*dy0 - 1.405f);
    float cosw0 = fminf(fmaxf(-tanlat*__tanf(decl0), -0.9999f), 0.9999f);
    float pet_c = fmaxf(HAMON*29.8f*(acosf(cosw0)*H24_PI)
                        *0.6108f*__expf(17.27f*ta_c*frcp(ta_c + 237.3f))
                        *frcp(ta_c + 273.2f), 0.0f);
    float mf_c  = mfa + mfb*__sinf(TWO_PI_366*dy0);

    for (int t = 0; t < T; ++t) {
        const int tn = min(t + 1, T - 1);
        float pr_n = prcp[(size_t)n*T + tn];
        float ta_n = tavg[(size_t)n*T + tn];
        float dy_n = (float)doy[(size_t)n*T + tn];
        const float pr = pr_c, ta = ta_c, pet = pet_c, mf = mf_c;

        bool is_snow = (ta <= PXTEMP);
        float ps    = is_snow ? pr*SCF : 0.0f;
        float prain = is_snow ? 0.0f   : pr;
        wi += ps;
        ati += TIPM*(fminf(ta, 0.0f) - ati);
        float mros = mrosk*fmaxf(ta, 0.0f)*((!is_snow && wi > 0.0f) ? prain : 0.0f);
        float melt = fminf(fmaxf(mf*fmaxf(ta - MBASE, 0.0f) + mros - NMF*fmaxf(-ati, 0.0f), 0.0f), wi);
        wi -= melt;
        float gm = fminf(DAYGM, wi);
        wi -= gm;
        float rop   = (wi > 0.0f) ? prain : 0.0f;
        float rfree = prain - rop;
        wq += melt + rop;
        float outq = fmaxf(wq - PLWHC*wi, 0.0f);
        wq -= outq;
        float eff = outq + gm + rfree;

        float e1 = fminf(pet*uztwc*inv_uztwm, uztwc);
        uztwc -= e1;
        float red = pet - e1;
        float e2 = fminf(red, uzfwc);
        uzfwc -= e2; red -= e2;
        float e3 = fminf(red*lztwc*inv_twm, lztwc);
        lztwc -= e3;
        float roimp  = eff*PCTIM;
        float padimp = eff*ADIMP;
        adimc += padimp;
        float ratio = fminf(fmaxf(adimc*inv_twm, 0.0f), 1.0f);
        float adsur = padimp*ratio*ratio;
        adimc = fminf(adimc - adsur, twm_sum);
        float surf = roimp + adsur;
        float base = 0.0f;
        float pinc = eff*pinc_fac;
        #pragma unroll
        for (int inc = 0; inc < N_INC; ++inc) {
            float bfp = lzfpc*kp;
            float bfs = lzfsc*ks;
            lzfpc -= bfp; lzfsc -= bfs;
            base += (bfp + bfs)*inv_side;
            float qif = uzfwc*ku;
            uzfwc -= qif; surf += qif;
            float lz_def = (LZTWM - lztwc) + (LZFPM - lzfpc) + (LZFSM - lzfsc);
            float defr = fminf(fmaxf(lz_def*inv_lzmax, 1e-6f), 1.0f);
            float perc = pm*fmaf(ZPERC, __expf(REXP*__logf(defr)), 1.0f)*uzfwc;
            perc = fminf(fminf(perc, uzfwc), fmaxf(lz_def, 0.0f));
            uzfwc -= perc;
            float pfree = perc*PFREE;
            lztwc += perc - pfree;
            float ex = fmaxf(lztwc - LZTWM, 0.0f);
            lztwc -= ex; pfree += ex;
            float dp  = fmaxf(LZFPM - lzfpc, 0.0f);
            float dsx = fmaxf(LZFSM - lzfsc, 0.0f);
            float fr  = dp*frcp(fmaxf(dp + dsx, 1e-6f));
            lzfpc += pfree*fr;
            lzfsc += pfree*(1.0f - fr);
            float exq = fmaxf(lzfpc - LZFPM, 0.0f);
            lzfpc -= exq; lzfsc += exq;
            float exs = fmaxf(lzfsc - LZFSM, 0.0f);
            lzfsc -= exs; surf += exs;
            uztwc += pinc;
            float exu = fmaxf(uztwc - UZTWM, 0.0f);
            uztwc -= exu; uzfwc += exu;
            float exf = fmaxf(uzfwc - UZFWM, 0.0f);
            uzfwc -= exf; surf += exf;
        }

        if (SPLIT) {
            surfA[(size_t)n*T + t] = surf;
            baseA[(size_t)n*T + t] = base;
        } else {
            float qv = uh[0]*surf;
            #pragma unroll
            for (int l = 1; l < UH_LEN; ++l) qv = fmaf(uh[l], hist[l-1], qv);
            #pragma unroll
            for (int l = UH_LEN-2; l >= 1; --l) hist[l] = hist[l-1];
            hist[0] = surf;
            qv += base;
            q_unit[(size_t)n*T + t] = qv;
            atomicAdd(&q_gauge[(size_t)bi*T + t], qv*wA);
            atomicAdd(&q_base [(size_t)bi*T + t], base*wA);
        }

        float decl = 0.4093f*__sinf(TWO_PI_365*dy_n - 1.405f);
        float cosw = fminf(fmaxf(-tanlat*__tanf(decl), -0.9999f), 0.9999f);
        pet_c = fmaxf(HAMON*29.8f*(acosf(cosw)*H24_PI)
                      *0.6108f*__expf(17.27f*ta_n*frcp(ta_n + 237.3f))
                      *frcp(ta_n + 273.2f), 0.0f);
        mf_c = mfa + mfb*__sinf(TWO_PI_366*dy_n);
        pr_c = pr_n; ta_c = ta_n;
    }
}

// ---------------------------------------------------------------------------
// Routing + gauge segment-sum: fully parallel over (n, t).
// ---------------------------------------------------------------------------
template<bool PACKED>
__global__ __launch_bounds__(256) void route_kernel(
    const float2* __restrict__ sbA,
    const float* __restrict__ surfA, const float* __restrict__ baseA,
    const float* __restrict__ P, const float* __restrict__ area_w,
    const int* __restrict__ basin_idx,
    float* __restrict__ out, int N, int T, int B)
{
    __shared__ float uh_sh[UH_LEN];
    __shared__ float wA_sh;
    __shared__ int   bi_sh;

    const int n = blockIdx.y;
    const int t = blockIdx.x*256 + threadIdx.x;

    if (threadIdx.x == 0) {
        float UH_N = P[28*N + n], UH_TAU = P[29*N + n];
        float inv_tau = frcp(UH_TAU);
        float tmp[UH_LEN], s = 0.f;
        #pragma unroll
        for (int l = 0; l < UH_LEN; ++l) {
            tmp[l] = __expf((UH_N - 1.0f)*LOGT[l] - (float)(l+1)*inv_tau);
            s += tmp[l];
        }
        float is = frcp(s);
        #pragma unroll
        for (int l = 0; l < UH_LEN; ++l) uh_sh[l] = tmp[l]*is;
        wA_sh = area_w[n];
        bi_sh = basin_idx[n];
    }
    __syncthreads();
    if (t >= T) return;

    float base, acc = 0.f;
    if (PACKED) {
        const float2* sb = sbA + (size_t)n*T;
        base = sb[t].y;
        #pragma unroll
        for (int l = 0; l < UH_LEN; ++l) {
            int tt = t - l;
            if (tt >= 0) acc = fmaf(uh_sh[l], sb[tt].x, acc);
        }
    } else {
        base = baseA[(size_t)n*T + t];
        #pragma unroll
        for (int l = 0; l < UH_LEN; ++l) {
            int tt = t - l;
            if (tt >= 0) acc = fmaf(uh_sh[l], surfA[(size_t)n*T + tt], acc);
        }
    }
    const float qv = acc + base;

    float* q_gauge = out;
    float* q_base  = out + (size_t)B*T;
    float* q_unit  = out + (size_t)2*B*T;

    q_unit[(size_t)n*T + t] = qv;
    atomicAdd(&q_gauge[(size_t)bi_sh*T + t], qv*wA_sh);
    atomicAdd(&q_base [(size_t)bi_sh*T + t], base*wA_sh);
}

static inline size_t align256(size_t x){ return (x + 255) & ~(size_t)255; }

extern "C" void kernel_launch(void* const* d_in, const int* in_sizes, int n_in,
                              void* d_out, int out_size, void* d_ws, size_t ws_size,
                              hipStream_t stream) {
    const float* x_dyn    = (const float*)d_in[0];
    const float* x_static = (const float*)d_in[1];
    const float* prcp     = (const float*)d_in[2];
    const float* tavg     = (const float*)d_in[3];
    const int*   doy      = (const int*)  d_in[4];
    const float* elev_m   = (const float*)d_in[5];
    const float* lat_rad  = (const float*)d_in[6];
    const float* area_w   = (const float*)d_in[7];
    const int*   basin_ix = (const int*)  d_in[8];
    const float* Wih      = (const float*)d_in[10];
    const float* Whh      = (const float*)d_in[11];
    const float* b_lstm   = (const float*)d_in[12];
    const float* Ws       = (const float*)d_in[13];
    const float* bs       = (const float*)d_in[14];
    const float* Wout     = (const float*)d_in[15];
    const float* bout     = (const float*)d_in[16];

    const int N = in_sizes[7];
    const int T = in_sizes[2] / N;
    const int DSTAT = in_sizes[1] / N;
    const size_t NT = (size_t)N * T;
    const int B = (out_size - (int)NT) / (2 * T);

    char* wsb = (char*)d_ws;
    float* params = (float*)wsb;
    const size_t off_prm = align256(30*(size_t)N*sizeof(float));

    // tier0: params | xb(16NT) | pack(16NT) | sb(8NT)
    const size_t off_xb0   = off_prm;
    const size_t off_pack0 = align256(off_xb0 + NT*16);
    const size_t off_sb0   = align256(off_pack0 + NT*16);
    const size_t need0     = off_sb0 + NT*8;
    // tier1: params | pack | sb (no xb)
    const size_t off_pack1 = off_prm;
    const size_t off_sb1   = align256(off_pack1 + NT*16);
    const size_t need1     = off_sb1 + NT*8;
    // tier2: params | surf | base
    const size_t off_surf2 = off_prm;
    const size_t off_base2 = off_surf2 + NT*4;
    const size_t need2     = off_base2 + NT*4;

    const int tier = (ws_size >= need0) ? 0 : (ws_size >= need1) ? 1 :
                     (ws_size >= need2) ? 2 : 3;

    float* out = (float*)d_out;
    const int zc = 2 * B * T;
    zero_kernel<<<(zc + 255)/256, 256, 0, stream>>>(out, zc);

    const int blocks_lstm = (N + 15) / 16;
    const int pblocks = (N + 63) / 64;
    dim3 rg((T + 255)/256, N);

    if (tier == 0) {
        unsigned short* xbp = (unsigned short*)(wsb + off_xb0);
        float4* pack = (float4*)(wsb + off_pack0);
        float2* sbA  = (float2*)(wsb + off_sb0);
        xpack_kernel<<<(int)((NT + 255)/256), 256, 0, stream>>>(x_dyn, xbp, NT);
        lstm_kernel<true><<<blocks_lstm, 256, 0, stream>>>(
            x_dyn, xbp, x_static, Wih, Whh, b_lstm, Ws, bs, Wout, bout,
            params, N, T, DSTAT);
        pack_kernel<<<rg, 256, 0, stream>>>(prcp, tavg, doy, lat_rad, params, pack, N, T);
        physics_fast_kernel<<<pblocks, 64, 0, stream>>>(elev_m, params, pack, sbA, N, T);
        route_kernel<true><<<rg, 256, 0, stream>>>(sbA, nullptr, nullptr, params, area_w,
                                                   basin_ix, out, N, T, B);
    } else if (tier == 1) {
        float4* pack = (float4*)(wsb + off_pack1);
        float2* sbA  = (float2*)(wsb + off_sb1);
        lstm_kernel<false><<<blocks_lstm, 256, 0, stream>>>(
            x_dyn, nullptr, x_static, Wih, Whh, b_lstm, Ws, bs, Wout, bout,
            params, N, T, DSTAT);
        pack_kernel<<<rg, 256, 0, stream>>>(prcp, tavg, doy, lat_rad, params, pack, N, T);
        physics_fast_kernel<<<pblocks, 64, 0, stream>>>(elev_m, params, pack, sbA, N, T);
        route_kernel<true><<<rg, 256, 0, stream>>>(sbA, nullptr, nullptr, params, area_w,
                                                   basin_ix, out, N, T, B);
    } else if (tier == 2) {
        float* surfA = (float*)(wsb + off_surf2);
        float* baseA = (float*)(wsb + off_base2);
        lstm_kernel<false><<<blocks_lstm, 256, 0, stream>>>(
            x_dyn, nullptr, x_static, Wih, Whh, b_lstm, Ws, bs, Wout, bout,
            params, N, T, DSTAT);
        physics_kernel<true><<<pblocks, 64, 0, stream>>>(
            prcp, tavg, doy, elev_m, lat_rad, area_w, basin_ix, params,
            surfA, baseA, out, N, T, B);
        route_kernel<false><<<rg, 256, 0, stream>>>(nullptr, surfA, baseA, params, area_w,
                                                    basin_ix, out, N, T, B);
    } else {
        lstm_kernel<false><<<blocks_lstm, 256, 0, stream>>>(
            x_dyn, nullptr, x_static, Wih, Whh, b_lstm, Ws, bs, Wout, bout,
            params, N, T, DSTAT);
        physics_kernel<false><<<pblocks, 64, 0, stream>>>(
            prcp, tavg, doy, elev_m, lat_rad, area_w, basin_ix, params,
            nullptr, nullptr, out, N, T, B);
    }
}